// Round 5
// baseline (297.521 us; speedup 1.0000x reference)
//
#include <hip/hip_runtime.h>
#include <hip/hip_bf16.h>

// AAConv2d: N=8, CIN=256, COUT=512, HEADS=8, DK=DV=256, MAP=32, KS=3, PAD=1
// DKH=DVH=32, CONV_OUT=256, HW=1024, K_conv = 9*256 = 2304 (order: t9=ky*3+kx major, c minor)

typedef __attribute__((ext_vector_type(8))) __bf16 bf16x8;
typedef __attribute__((ext_vector_type(4))) float f32x4;
typedef unsigned short u16;
typedef unsigned int u32;
typedef __attribute__((ext_vector_type(8))) u16 u16x8;

#define GLD(gp, lp) __builtin_amdgcn_global_load_lds( \
    (const __attribute__((address_space(1))) u32*)(gp), \
    (__attribute__((address_space(3))) u32*)(lp), 16, 0, 0)

static __device__ __forceinline__ u16 f2bf(float f) {
  u32 u = __builtin_bit_cast(u32, f);
  u += 0x7fffu + ((u >> 16) & 1u);   // round-to-nearest-even
  return (u16)(u >> 16);
}
static __device__ __forceinline__ float bf2f(u16 h) {
  return __builtin_bit_cast(float, (u32)h << 16);
}

// ---------------- cast + reorder weights to bf16 (coalesced) ----------------
// W9[1024][2304]: rows 0-255 conv_w, 256-511 q_w, 512-767 k_w, 768-1023 v_w
// column order: t9*256 + c  (was c*9 + t9 in the fp32 source). One block per row.
__global__ __launch_bounds__(256) void k_cast_w(
    const float* __restrict__ conv_w, const float* __restrict__ q_w,
    const float* __restrict__ k_w, const float* __restrict__ v_w,
    const float* __restrict__ attn_w, u16* __restrict__ W9, u16* __restrict__ W1) {
  __shared__ float t[2304];
  int row = blockIdx.x;
  const float* src = row < 256 ? conv_w : row < 512 ? q_w : row < 768 ? k_w : v_w;
  const float* sr = src + (row & 255) * 2304;
#pragma unroll
  for (int i = threadIdx.x; i < 2304; i += 256) t[i] = sr[i];   // coalesced [c][t9]
  __syncthreads();
  u16* dr = W9 + row * 2304;
#pragma unroll
  for (int i = threadIdx.x; i < 2304; i += 256) {
    int t9 = i >> 8, c = i & 255;
    dr[i] = f2bf(t[c * 9 + t9]);
  }
  if (row < 256) W1[row * 256 + threadIdx.x] = f2bf(attn_w[row * 256 + threadIdx.x]);
}

// ---------------- x transpose: xT[n][s=y*32+x][c] bf16, + zero page ----------------
__global__ void k_xT(const float* __restrict__ x, u16* __restrict__ xT,
                     u16* __restrict__ zpage) {
  if (blockIdx.x == 0 && threadIdx.x < 512) zpage[threadIdx.x] = 0;
  __shared__ float t[32][33];
  int b = blockIdx.x;                       // 2048 blocks: n(8) x cb(8) x sb(32)
  int sb = b & 31, cb = (b >> 5) & 7, n = b >> 8;
  int s0 = sb << 5, c0 = cb << 5;
  int ls = threadIdx.x & 31, lc = threadIdx.x >> 5;  // lc 0..7
#pragma unroll
  for (int i = 0; i < 4; ++i) {
    int c = lc + i * 8;
    t[c][ls] = x[(((n << 8) + c0 + c) << 10) + s0 + ls];
  }
  __syncthreads();
#pragma unroll
  for (int i = 0; i < 4; ++i) {
    int s = lc + i * 8;
    xT[(((n << 10) + s0 + s) << 8) + c0 + ls] = f2bf(t[ls][s]);
  }
}

// ---------------- implicit conv GEMM: M=1024 (co), N=8192 (n*1024+s), K=2304 ----------------
// A = W9 (row-major, K contiguous). B[ns][t9*256+c] = xT[n][s + dy*32 + dx][c] (0 at borders),
// staged via per-lane global addresses + zero-page redirect (LDS dest stays linear).
// Double-buffered LDS, ONE drain+barrier per K-step: STAGE(t+1) issued before compute(t).
__global__ __launch_bounds__(256) void k_gemm_conv(
    const u16* __restrict__ A, const u16* __restrict__ xT, const u16* __restrict__ zpage,
    float* __restrict__ out,
    u16* __restrict__ qb, u16* __restrict__ kb, u16* __restrict__ vb,
    const float* __restrict__ conv_b, const float* __restrict__ q_b,
    const float* __restrict__ k_b, const float* __restrict__ v_b) {
  __shared__ u16 As[2][8192], Bs[2][8192];   // 64 KB
  f32x4 acc[4][4] = {};
  const int tid = threadIdx.x;
  const int wave = tid >> 6, lane = tid & 63;
  const int wr = wave >> 1, wc = wave & 1;
  const int lr = lane & 15, lk = lane >> 4;
  const int srow = lane >> 3;          // staging row within 8-row segment
  const int scol = (lane & 7) << 3;    // staging col (elements)
  const int bm = blockIdx.x, bn = blockIdx.y;

  // per-lane B-row geometry (constant over K): 4 segments, rows seg*8+srow
  int bn_y[4], bn_x[4], bn_base[4];
#pragma unroll
  for (int i = 0; i < 4; ++i) {
    int seg = i * 4 + wave;
    int col = bn * 128 + seg * 8 + srow;       // ns
    int n = col >> 10, s = col & 1023;
    bn_y[i] = s >> 5;
    bn_x[i] = s & 31;
    bn_base[i] = n << 10;
  }

  auto stage = [&](int buf, int k0) {
    int t9 = k0 >> 8;
    int dy = t9 / 3 - 1, dx = t9 - (t9 / 3) * 3 - 1;
    int c0 = k0 & 255;
#pragma unroll
    for (int i = 0; i < 4; ++i) {
      int seg = i * 4 + wave;
      GLD(A + (bm * 128 + seg * 8 + srow) * 2304 + k0 + scol, &As[buf][seg * 512]);
      int sy = bn_y[i] + dy, sx = bn_x[i] + dx;
      bool ok = ((u32)sy < 32u) && ((u32)sx < 32u);
      const u16* src = ok ? (xT + ((bn_base[i] + (sy << 5) + sx) << 8) + c0 + scol)
                          : (zpage + scol);
      GLD(src, &Bs[buf][seg * 512]);
    }
  };

  stage(0, 0);
  __syncthreads();          // drains vmcnt(0) lgkmcnt(0) then s_barrier
  int cur = 0;
  for (int kt = 0; kt < 36; ++kt) {
    if (kt + 1 < 36) stage(cur ^ 1, (kt + 1) * 64);   // prefetch overlaps compute below
#pragma unroll
    for (int kk = 0; kk < 2; ++kk) {
      bf16x8 af[4], bv[4];
#pragma unroll
      for (int m = 0; m < 4; ++m)
        af[m] = *(const bf16x8*)&As[cur][(wr * 64 + m * 16 + lr) * 64 + kk * 32 + lk * 8];
#pragma unroll
      for (int n = 0; n < 4; ++n)
        bv[n] = *(const bf16x8*)&Bs[cur][(wc * 64 + n * 16 + lr) * 64 + kk * 32 + lk * 8];
#pragma unroll
      for (int m = 0; m < 4; ++m)
#pragma unroll
        for (int n = 0; n < 4; ++n)
          acc[m][n] = __builtin_amdgcn_mfma_f32_16x16x32_bf16(af[m], bv[n], acc[m][n], 0, 0, 0);
    }
    __syncthreads();        // one drain+barrier per K-step
    cur ^= 1;
  }

  const int row0 = bm * 128 + wr * 64 + lk * 4;  // C/D: row=(lane>>4)*4+j
  const int col0 = bn * 128 + wc * 64 + lr;      // C/D: col=lane&15
#pragma unroll
  for (int m = 0; m < 4; ++m) {
#pragma unroll
    for (int n = 0; n < 4; ++n) {
      int col = col0 + n * 16;
      int nn = col >> 10, s = col & 1023;
#pragma unroll
      for (int j = 0; j < 4; ++j) {
        int c = row0 + m * 16 + j;
        float v = acc[m][n][j];
        if (c < 256) {
          out[((nn << 9) + c) * 1024 + s] = v + conv_b[c];
        } else if (c < 512) {
          int cc = c - 256;
          qb[((((nn << 3) + (cc >> 5)) << 10) + s) * 32 + (cc & 31)] = f2bf(v + q_b[cc]);
        } else if (c < 768) {
          int cc = c - 512;
          kb[((((nn << 3) + (cc >> 5)) << 10) + s) * 32 + (cc & 31)] = f2bf(v + k_b[cc]);
        } else {
          int cc = c - 768;
          vb[((nn << 8) + cc) * 1024 + s] = f2bf(v + v_b[cc]);
        }
      }
    }
  }
}

// ---------------- rel-position bias tables ----------------
// one thread per pos: Bw[pos][r] = q(pos).wm[r-x+31], Bh[pos][r] = q(pos).hm[r-y+31]
__global__ __launch_bounds__(256) void k_bias(const u16* __restrict__ qb,
                                              const float* __restrict__ wm,
                                              const float* __restrict__ hm,
                                              float* __restrict__ Bw, float* __restrict__ Bh) {
  int pos = blockIdx.x * blockDim.x + threadIdx.x;  // 65536
  int s = pos & 1023;
  int y = s >> 5, xx = s & 31;
  float q[32];
  const u16x8* q8 = (const u16x8*)(qb + pos * 32);
#pragma unroll
  for (int v = 0; v < 4; ++v) {
    u16x8 w = q8[v];
#pragma unroll
    for (int e = 0; e < 8; ++e) q[v * 8 + e] = bf2f(w[e]);
  }
  float* bwo = Bw + pos * 32;
  float* bho = Bh + pos * 32;
#pragma unroll 4
  for (int r = 0; r < 32; ++r) {
    const f32x4* wr = (const f32x4*)(wm + (r - xx + 31) * 32);
    const f32x4* hr = (const f32x4*)(hm + (r - y + 31) * 32);
    float aw = 0.f, ah = 0.f;
#pragma unroll
    for (int i = 0; i < 8; ++i) {
      f32x4 wv = wr[i], hv = hr[i];
#pragma unroll
      for (int e = 0; e < 4; ++e) {
        float qd = q[i * 4 + e];
        aw += qd * wv[e];
        ah += qd * hv[e];
      }
    }
    bwo[r] = aw;
    bho[r] = ah;
  }
}

// ---------------- flash attention with rel-pos bias ----------------
// 1 wave = 16 queries of one (n,h). S = (Q Kt + Bh + Bw) * 32^-0.5; online softmax;
// O = softmax(S) V. Output scattered per reference reshape: AMT[(n,s'=(q&31)*32+d)][h*32+(q>>5)].
__global__ __launch_bounds__(256) void k_attn(
    const u16* __restrict__ qb, const u16* __restrict__ kb, const u16* __restrict__ vb,
    const float* __restrict__ Bw, const float* __restrict__ Bh, u16* __restrict__ AMT) {
  __shared__ u16 Pl[4][1024];  // per-wave P tile 16x64
  const int wave = threadIdx.x >> 6, lane = threadIdx.x & 63;
  const int task = blockIdx.x * 4 + wave;  // 4096 tasks = 64 nh * 64 q-groups
  const int nh = task >> 6, qg = task & 63;
  const int n = nh >> 3, h = nh & 7;
  const int qbase = qg << 4;
  const int lr = lane & 15, lg = lane >> 4;

  // Q A-frag: row q = lane&15, k-span d = (lane>>4)*8
  bf16x8 aq = *(const bf16x8*)&qb[((nh << 10) + qbase + lr) * 32 + lg * 8];

  // Bw preload (constant over k-tiles): q row = qbase+lg*4+j, kx = p*16+lr
  float Bwr[2][4];
#pragma unroll
  for (int p = 0; p < 2; ++p)
#pragma unroll
    for (int j = 0; j < 4; ++j)
      Bwr[p][j] = Bw[((nh << 10) + qbase + lg * 4 + j) * 32 + p * 16 + lr];

  float mrow[4] = {-1e30f, -1e30f, -1e30f, -1e30f};
  float lrow[4] = {0.f, 0.f, 0.f, 0.f};
  f32x4 o[2] = {};
  u16* pl = Pl[wave];

  for (int kt = 0; kt < 16; ++kt) {
    f32x4 zero = {0.f, 0.f, 0.f, 0.f};
    f32x4 sf_[4];
#pragma unroll
    for (int f = 0; f < 4; ++f) {
      bf16x8 bk = *(const bf16x8*)&kb[((nh << 10) + (kt << 6) + f * 16 + lr) * 32 + lg * 8];
      sf_[f] = __builtin_amdgcn_mfma_f32_16x16x32_bf16(aq, bk, zero, 0, 0, 0);
    }
    float Bhr[2][4];  // ky = kt*2 + p
#pragma unroll
    for (int p = 0; p < 2; ++p)
#pragma unroll
      for (int j = 0; j < 4; ++j)
        Bhr[p][j] = Bh[((nh << 10) + qbase + lg * 4 + j) * 32 + (kt << 1) + p];
    float tv[4][4];
#pragma unroll
    for (int f = 0; f < 4; ++f)   // k col = f*16+lr -> kx=(f&1)*16+lr, ky_local=f>>1
#pragma unroll
      for (int j = 0; j < 4; ++j)
        tv[f][j] = (sf_[f][j] + Bhr[f >> 1][j] + Bwr[f & 1][j]) * 0.17677669529663687f;

    float pv[4][4], sf[4];
#pragma unroll
    for (int j = 0; j < 4; ++j) {
      float vmax = fmaxf(fmaxf(tv[0][j], tv[1][j]), fmaxf(tv[2][j], tv[3][j]));
#pragma unroll
      for (int d = 1; d < 16; d <<= 1) vmax = fmaxf(vmax, __shfl_xor(vmax, d, 64));
      float mn = fmaxf(mrow[j], vmax);
      sf[j] = __expf(mrow[j] - mn);
      mrow[j] = mn;
      float sum = 0.f;
#pragma unroll
      for (int f = 0; f < 4; ++f) {
        float e = __expf(tv[f][j] - mn);
        pv[f][j] = e;
        sum += e;
      }
#pragma unroll
      for (int d = 1; d < 16; d <<= 1) sum += __shfl_xor(sum, d, 64);
      lrow[j] = lrow[j] * sf[j] + sum;
    }
#pragma unroll
    for (int dn = 0; dn < 2; ++dn)
#pragma unroll
      for (int j = 0; j < 4; ++j) o[dn][j] *= sf[j];

    // P: C-layout -> LDS -> A-layout (per-wave region, in-order DS ops)
#pragma unroll
    for (int f = 0; f < 4; ++f)
#pragma unroll
      for (int j = 0; j < 4; ++j)
        pl[(lg * 4 + j) * 64 + f * 16 + lr] = f2bf(pv[f][j]);
    asm volatile("s_waitcnt lgkmcnt(0)" ::: "memory");
    __builtin_amdgcn_sched_barrier(0);   // rule #18: keep dependent reads below the wait
    bf16x8 pa0 = *(const bf16x8*)&pl[lr * 64 + lg * 8];
    bf16x8 pa1 = *(const bf16x8*)&pl[lr * 64 + 32 + lg * 8];
#pragma unroll
    for (int dn = 0; dn < 2; ++dn) {
      bf16x8 bv0 = *(const bf16x8*)&vb[((n << 8) + (h << 5) + dn * 16 + lr) * 1024 + (kt << 6) + lg * 8];
      o[dn] = __builtin_amdgcn_mfma_f32_16x16x32_bf16(pa0, bv0, o[dn], 0, 0, 0);
      bf16x8 bv1 = *(const bf16x8*)&vb[((n << 8) + (h << 5) + dn * 16 + lr) * 1024 + (kt << 6) + 32 + lg * 8];
      o[dn] = __builtin_amdgcn_mfma_f32_16x16x32_bf16(pa1, bv1, o[dn], 0, 0, 0);
    }
  }
#pragma unroll
  for (int dn = 0; dn < 2; ++dn)
#pragma unroll
    for (int j = 0; j < 4; ++j) {
      int q = qbase + lg * 4 + j;
      int d = dn * 16 + lr;
      float v = o[dn][j] / lrow[j];
      // reference reshape: attn_maps[n][h*32+(q>>5)][y=q&31][x=d]; AMT[ns][c] (B^T for 1x1 GEMM)
      AMT[((n << 10) + ((q & 31) << 5) + d) * 256 + (h << 5) + (q >> 5)] = f2bf(v);
    }
}

// ---------------- generic 128x128 GEMM core (C = A * B^T), double-buffered ----------------
static __device__ __forceinline__ void gemm_core(const u16* __restrict__ A,
                                                 const u16* __restrict__ B, int K,
                                                 u16 (*As)[8192], u16 (*Bs)[8192],
                                                 f32x4 acc[4][4]) {
  const int tid = threadIdx.x;
  const int wave = tid >> 6, lane = tid & 63;
  const int wr = wave >> 1, wc = wave & 1;
  const int lr = lane & 15, lk = lane >> 4;
  const int srow = lane >> 3;
  const int scol = (lane & 7) << 3;
  const int bm = blockIdx.x, bn = blockIdx.y;
  auto stage = [&](int buf, int k0) {
#pragma unroll
    for (int i = 0; i < 4; ++i) {
      int seg = i * 4 + wave;
      GLD(A + (bm * 128 + seg * 8 + srow) * K + k0 + scol, &As[buf][seg * 512]);
      GLD(B + (bn * 128 + seg * 8 + srow) * K + k0 + scol, &Bs[buf][seg * 512]);
    }
  };
  stage(0, 0);
  __syncthreads();
  int cur = 0;
  const int nt = K >> 6;
  for (int kt = 0; kt < nt; ++kt) {
    if (kt + 1 < nt) stage(cur ^ 1, (kt + 1) << 6);
#pragma unroll
    for (int kk = 0; kk < 2; ++kk) {
      bf16x8 af[4], bv[4];
#pragma unroll
      for (int m = 0; m < 4; ++m)
        af[m] = *(const bf16x8*)&As[cur][(wr * 64 + m * 16 + lr) * 64 + kk * 32 + lk * 8];
#pragma unroll
      for (int n = 0; n < 4; ++n)
        bv[n] = *(const bf16x8*)&Bs[cur][(wc * 64 + n * 16 + lr) * 64 + kk * 32 + lk * 8];
#pragma unroll
      for (int m = 0; m < 4; ++m)
#pragma unroll
        for (int n = 0; n < 4; ++n)
          acc[m][n] = __builtin_amdgcn_mfma_f32_16x16x32_bf16(af[m], bv[n], acc[m][n], 0, 0, 0);
    }
    __syncthreads();
    cur ^= 1;
  }
}

// ---------------- 1x1 conv GEMM: M=256, N=8192, K=256 -> out channels 256..511 ----------------
__global__ __launch_bounds__(256) void k_gemm_out(
    const u16* __restrict__ A, const u16* __restrict__ B, float* __restrict__ out,
    const float* __restrict__ attn_b) {
  __shared__ u16 As[2][8192], Bs[2][8192];
  f32x4 acc[4][4] = {};
  gemm_core(A, B, 256, As, Bs, acc);
  const int tid = threadIdx.x;
  const int wave = tid >> 6, lane = tid & 63;
  const int wr = wave >> 1, wc = wave & 1;
  const int lr = lane & 15, lk = lane >> 4;
  const int row0 = blockIdx.x * 128 + wr * 64 + lk * 4;
  const int col0 = blockIdx.y * 128 + wc * 64 + lr;
#pragma unroll
  for (int m = 0; m < 4; ++m) {
#pragma unroll
    for (int n = 0; n < 4; ++n) {
      int col = col0 + n * 16;
      int nn = col >> 10, s = col & 1023;
#pragma unroll
      for (int j = 0; j < 4; ++j) {
        int c = row0 + m * 16 + j;
        out[((nn << 9) + 256 + c) * 1024 + s] = acc[m][n][j] + attn_b[c];
      }
    }
  }
}

extern "C" void kernel_launch(void* const* d_in, const int* in_sizes, int n_in,
                              void* d_out, int out_size, void* d_ws, size_t ws_size,
                              hipStream_t stream) {
  const float* x      = (const float*)d_in[0];
  const float* conv_w = (const float*)d_in[1];
  const float* conv_b = (const float*)d_in[2];
  const float* q_w    = (const float*)d_in[3];
  const float* q_b    = (const float*)d_in[4];
  const float* k_w    = (const float*)d_in[5];
  const float* k_b    = (const float*)d_in[6];
  const float* v_w    = (const float*)d_in[7];
  const float* v_b    = (const float*)d_in[8];
  const float* attn_w = (const float*)d_in[9];
  const float* attn_b = (const float*)d_in[10];
  const float* wm     = (const float*)d_in[11];
  const float* hm     = (const float*)d_in[12];
  float* out = (float*)d_out;
  char* ws = (char*)d_ws;

  // workspace layout (bytes), total ~42.6 MB
  u16*   W9   = (u16*)(ws + 0);         // 1024*2304*2 = 4,718,592
  u16*   W1   = (u16*)(ws + 4718592);   //  256*256*2  =   131,072
  u16*   xT   = (u16*)(ws + 4849664);   // 8192*256*2  = 4,194,304
  u16*   zpg  = (u16*)(ws + 9043968);   // 512*2       =     1,024
  u16*   qbf  = (u16*)(ws + 9044992);   // 64*1024*32*2= 4,194,304
  u16*   kbf  = (u16*)(ws + 13239296);  //               4,194,304
  u16*   vbf  = (u16*)(ws + 17433600);  //               4,194,304
  float* Bw   = (float*)(ws + 21627904);// 2M*4 =        8,388,608
  float* Bh   = (float*)(ws + 30016512);//               8,388,608
  u16*   AMT  = (u16*)(ws + 38405120);  // 8192*256*2 =  4,194,304

  hipLaunchKernelGGL(k_cast_w, dim3(1024), dim3(256), 0, stream,
                     conv_w, q_w, k_w, v_w, attn_w, W9, W1);
  hipLaunchKernelGGL(k_xT, dim3(2048), dim3(256), 0, stream, x, xT, zpg);
  hipLaunchKernelGGL(k_gemm_conv, dim3(8, 64), dim3(256), 0, stream,
                     W9, xT, zpg, out, qbf, kbf, vbf, conv_b, q_b, k_b, v_b);
  hipLaunchKernelGGL(k_bias, dim3(256), dim3(256), 0, stream, qbf, wm, hm, Bw, Bh);
  hipLaunchKernelGGL(k_attn, dim3(1024), dim3(256), 0, stream, qbf, kbf, vbf, Bw, Bh, AMT);
  hipLaunchKernelGGL(k_gemm_out, dim3(2, 64), dim3(256), 0, stream, W1, AMT, out, attn_b);
}

// Round 6
// 294.338 us; speedup vs baseline: 1.0108x; 1.0108x over previous
//
#include <hip/hip_runtime.h>
#include <hip/hip_bf16.h>

// AAConv2d: N=8, CIN=256, COUT=512, HEADS=8, DK=DV=256, MAP=32, KS=3, PAD=1
// DKH=DVH=32, CONV_OUT=256, HW=1024, K_conv = 9*256 = 2304 (order: t9=ky*3+kx major, c minor)

typedef __attribute__((ext_vector_type(8))) __bf16 bf16x8;
typedef __attribute__((ext_vector_type(4))) float f32x4;
typedef unsigned short u16;
typedef unsigned int u32;
typedef __attribute__((ext_vector_type(8))) u16 u16x8;

#define GLD(gp, lp) __builtin_amdgcn_global_load_lds( \
    (const __attribute__((address_space(1))) u32*)(gp), \
    (__attribute__((address_space(3))) u32*)(lp), 16, 0, 0)

static __device__ __forceinline__ u16 f2bf(float f) {
  u32 u = __builtin_bit_cast(u32, f);
  u += 0x7fffu + ((u >> 16) & 1u);   // round-to-nearest-even
  return (u16)(u >> 16);
}
static __device__ __forceinline__ float bf2f(u16 h) {
  return __builtin_bit_cast(float, (u32)h << 16);
}

// ---------------- cast + reorder weights to bf16 (coalesced) ----------------
// W9[1024][2304]: rows 0-255 conv_w, 256-511 q_w, 512-767 k_w, 768-1023 v_w
// column order: t9*256 + c  (was c*9 + t9 in the fp32 source). One block per row.
__global__ __launch_bounds__(256) void k_cast_w(
    const float* __restrict__ conv_w, const float* __restrict__ q_w,
    const float* __restrict__ k_w, const float* __restrict__ v_w,
    const float* __restrict__ attn_w, u16* __restrict__ W9, u16* __restrict__ W1) {
  __shared__ float t[2304];
  int row = blockIdx.x;
  const float* src = row < 256 ? conv_w : row < 512 ? q_w : row < 768 ? k_w : v_w;
  const float* sr = src + (row & 255) * 2304;
#pragma unroll
  for (int i = threadIdx.x; i < 2304; i += 256) t[i] = sr[i];   // coalesced [c][t9]
  __syncthreads();
  u16* dr = W9 + row * 2304;
#pragma unroll
  for (int i = threadIdx.x; i < 2304; i += 256) {
    int t9 = i >> 8, c = i & 255;
    dr[i] = f2bf(t[c * 9 + t9]);
  }
  if (row < 256) W1[row * 256 + threadIdx.x] = f2bf(attn_w[row * 256 + threadIdx.x]);
}

// ---------------- x transpose: xT[n][s=y*32+x][c] bf16, + zero page ----------------
__global__ void k_xT(const float* __restrict__ x, u16* __restrict__ xT,
                     u16* __restrict__ zpage) {
  if (blockIdx.x == 0 && threadIdx.x < 512) zpage[threadIdx.x] = 0;
  __shared__ float t[32][33];
  int b = blockIdx.x;                       // 2048 blocks: n(8) x cb(8) x sb(32)
  int sb = b & 31, cb = (b >> 5) & 7, n = b >> 8;
  int s0 = sb << 5, c0 = cb << 5;
  int ls = threadIdx.x & 31, lc = threadIdx.x >> 5;  // lc 0..7
#pragma unroll
  for (int i = 0; i < 4; ++i) {
    int c = lc + i * 8;
    t[c][ls] = x[(((n << 8) + c0 + c) << 10) + s0 + ls];
  }
  __syncthreads();
#pragma unroll
  for (int i = 0; i < 4; ++i) {
    int s = lc + i * 8;
    xT[(((n << 10) + s0 + s) << 8) + c0 + ls] = f2bf(t[ls][s]);
  }
}

// ---------------- implicit conv GEMM: M=1024 (co), N=8192 (n*1024+s), K=2304 ----------------
// A = W9 (row-major, K contiguous). B[ns][t9*256+c] = xT[n][s + dy*32 + dx][c] (0 at borders),
// staged via per-lane global addresses + zero-page redirect (LDS dest stays linear).
// 512 threads = 8 waves (2M x 4N of 64x32 sub-tiles) for 4 waves/SIMD residency;
// single-buffer, one stage + 2 barriers per K-step (R4-verified structure).
__global__ __launch_bounds__(512) void k_gemm_conv(
    const u16* __restrict__ A, const u16* __restrict__ xT, const u16* __restrict__ zpage,
    float* __restrict__ out,
    u16* __restrict__ qb, u16* __restrict__ kb, u16* __restrict__ vb,
    const float* __restrict__ conv_b, const float* __restrict__ q_b,
    const float* __restrict__ k_b, const float* __restrict__ v_b) {
  __shared__ u16 As[8192], Bs[8192];   // 32 KB
  f32x4 acc[4][2] = {};
  const int tid = threadIdx.x;
  const int wave = tid >> 6, lane = tid & 63;
  const int wr = wave >> 2, wc = wave & 3;     // wave grid 2 (M) x 4 (N)
  const int lr = lane & 15, lk = lane >> 4;
  const int srow = lane >> 3;          // staging row within 8-row segment
  const int scol = (lane & 7) << 3;    // staging col (elements)
  const int bm = blockIdx.x, bn = blockIdx.y;

  // per-lane B-row geometry (constant over K): 2 segments/wave, rows seg*8+srow
  int bn_y[2], bn_x[2], bn_base[2];
#pragma unroll
  for (int i = 0; i < 2; ++i) {
    int seg = i * 8 + wave;
    int col = bn * 128 + seg * 8 + srow;       // ns
    int n = col >> 10, s = col & 1023;
    bn_y[i] = s >> 5;
    bn_x[i] = s & 31;
    bn_base[i] = n << 10;
  }

  for (int k0 = 0; k0 < 2304; k0 += 64) {
    int t9 = k0 >> 8;
    int dy = t9 / 3 - 1, dx = t9 - (t9 / 3) * 3 - 1;
    int c0 = k0 & 255;
#pragma unroll
    for (int i = 0; i < 2; ++i) {
      int seg = i * 8 + wave;                  // 16 segments of 8 rows x 64 cols
      GLD(A + (bm * 128 + seg * 8 + srow) * 2304 + k0 + scol, As + seg * 512);
      int sy = bn_y[i] + dy, sx = bn_x[i] + dx;
      bool ok = ((u32)sy < 32u) && ((u32)sx < 32u);
      const u16* src = ok ? (xT + ((bn_base[i] + (sy << 5) + sx) << 8) + c0 + scol)
                          : (zpage + scol);
      GLD(src, Bs + seg * 512);
    }
    __syncthreads();
#pragma unroll
    for (int kk = 0; kk < 2; ++kk) {
      bf16x8 af[4], bv[2];
#pragma unroll
      for (int m = 0; m < 4; ++m)
        af[m] = *(const bf16x8*)&As[(wr * 64 + m * 16 + lr) * 64 + kk * 32 + lk * 8];
#pragma unroll
      for (int n = 0; n < 2; ++n)
        bv[n] = *(const bf16x8*)&Bs[(wc * 32 + n * 16 + lr) * 64 + kk * 32 + lk * 8];
#pragma unroll
      for (int m = 0; m < 4; ++m)
#pragma unroll
        for (int n = 0; n < 2; ++n)
          acc[m][n] = __builtin_amdgcn_mfma_f32_16x16x32_bf16(af[m], bv[n], acc[m][n], 0, 0, 0);
    }
    __syncthreads();
  }

  const int row0 = bm * 128 + wr * 64 + lk * 4;  // C/D: row=(lane>>4)*4+j
  const int col0 = bn * 128 + wc * 32 + lr;      // C/D: col=lane&15
#pragma unroll
  for (int m = 0; m < 4; ++m) {
#pragma unroll
    for (int n = 0; n < 2; ++n) {
      int col = col0 + n * 16;
      int nn = col >> 10, s = col & 1023;
#pragma unroll
      for (int j = 0; j < 4; ++j) {
        int c = row0 + m * 16 + j;
        float v = acc[m][n][j];
        if (c < 256) {
          out[((nn << 9) + c) * 1024 + s] = v + conv_b[c];
        } else if (c < 512) {
          int cc = c - 256;
          qb[((((nn << 3) + (cc >> 5)) << 10) + s) * 32 + (cc & 31)] = f2bf(v + q_b[cc]);
        } else if (c < 768) {
          int cc = c - 512;
          kb[((((nn << 3) + (cc >> 5)) << 10) + s) * 32 + (cc & 31)] = f2bf(v + k_b[cc]);
        } else {
          int cc = c - 768;
          vb[((nn << 8) + cc) * 1024 + s] = f2bf(v + v_b[cc]);
        }
      }
    }
  }
}

// ---------------- rel-position bias tables ----------------
// one thread per pos: Bw[pos][r] = q(pos).wm[r-x+31], Bh[pos][r] = q(pos).hm[r-y+31]
__global__ __launch_bounds__(256) void k_bias(const u16* __restrict__ qb,
                                              const float* __restrict__ wm,
                                              const float* __restrict__ hm,
                                              float* __restrict__ Bw, float* __restrict__ Bh) {
  int pos = blockIdx.x * blockDim.x + threadIdx.x;  // 65536
  int s = pos & 1023;
  int y = s >> 5, xx = s & 31;
  float q[32];
  const u16x8* q8 = (const u16x8*)(qb + pos * 32);
#pragma unroll
  for (int v = 0; v < 4; ++v) {
    u16x8 w = q8[v];
#pragma unroll
    for (int e = 0; e < 8; ++e) q[v * 8 + e] = bf2f(w[e]);
  }
  float* bwo = Bw + pos * 32;
  float* bho = Bh + pos * 32;
#pragma unroll 4
  for (int r = 0; r < 32; ++r) {
    const f32x4* wr = (const f32x4*)(wm + (r - xx + 31) * 32);
    const f32x4* hr = (const f32x4*)(hm + (r - y + 31) * 32);
    float aw = 0.f, ah = 0.f;
#pragma unroll
    for (int i = 0; i < 8; ++i) {
      f32x4 wv = wr[i], hv = hr[i];
#pragma unroll
      for (int e = 0; e < 4; ++e) {
        float qd = q[i * 4 + e];
        aw += qd * wv[e];
        ah += qd * hv[e];
      }
    }
    bwo[r] = aw;
    bho[r] = ah;
  }
}

// ---------------- flash attention with rel-pos bias ----------------
// 1 wave = 16 queries of one (n,h). S = (Q Kt + Bh + Bw) * 32^-0.5; online softmax;
// O = softmax(S) V. Output scattered per reference reshape: AMT[(n,s'=(q&31)*32+d)][h*32+(q>>5)].
__global__ __launch_bounds__(256) void k_attn(
    const u16* __restrict__ qb, const u16* __restrict__ kb, const u16* __restrict__ vb,
    const float* __restrict__ Bw, const float* __restrict__ Bh, u16* __restrict__ AMT) {
  __shared__ u16 Pl[4][1024];  // per-wave P tile 16x64
  const int wave = threadIdx.x >> 6, lane = threadIdx.x & 63;
  const int task = blockIdx.x * 4 + wave;  // 4096 tasks = 64 nh * 64 q-groups
  const int nh = task >> 6, qg = task & 63;
  const int n = nh >> 3, h = nh & 7;
  const int qbase = qg << 4;
  const int lr = lane & 15, lg = lane >> 4;

  // Q A-frag: row q = lane&15, k-span d = (lane>>4)*8
  bf16x8 aq = *(const bf16x8*)&qb[((nh << 10) + qbase + lr) * 32 + lg * 8];

  // Bw preload (constant over k-tiles): q row = qbase+lg*4+j, kx = p*16+lr
  float Bwr[2][4];
#pragma unroll
  for (int p = 0; p < 2; ++p)
#pragma unroll
    for (int j = 0; j < 4; ++j)
      Bwr[p][j] = Bw[((nh << 10) + qbase + lg * 4 + j) * 32 + p * 16 + lr];

  float mrow[4] = {-1e30f, -1e30f, -1e30f, -1e30f};
  float lrow[4] = {0.f, 0.f, 0.f, 0.f};
  f32x4 o[2] = {};
  u16* pl = Pl[wave];

  for (int kt = 0; kt < 16; ++kt) {
    f32x4 zero = {0.f, 0.f, 0.f, 0.f};
    f32x4 sf_[4];
#pragma unroll
    for (int f = 0; f < 4; ++f) {
      bf16x8 bk = *(const bf16x8*)&kb[((nh << 10) + (kt << 6) + f * 16 + lr) * 32 + lg * 8];
      sf_[f] = __builtin_amdgcn_mfma_f32_16x16x32_bf16(aq, bk, zero, 0, 0, 0);
    }
    float Bhr[2][4];  // ky = kt*2 + p
#pragma unroll
    for (int p = 0; p < 2; ++p)
#pragma unroll
      for (int j = 0; j < 4; ++j)
        Bhr[p][j] = Bh[((nh << 10) + qbase + lg * 4 + j) * 32 + (kt << 1) + p];
    float tv[4][4];
#pragma unroll
    for (int f = 0; f < 4; ++f)   // k col = f*16+lr -> kx=(f&1)*16+lr, ky_local=f>>1
#pragma unroll
      for (int j = 0; j < 4; ++j)
        tv[f][j] = (sf_[f][j] + Bhr[f >> 1][j] + Bwr[f & 1][j]) * 0.17677669529663687f;

    float pv[4][4], sf[4];
#pragma unroll
    for (int j = 0; j < 4; ++j) {
      float vmax = fmaxf(fmaxf(tv[0][j], tv[1][j]), fmaxf(tv[2][j], tv[3][j]));
#pragma unroll
      for (int d = 1; d < 16; d <<= 1) vmax = fmaxf(vmax, __shfl_xor(vmax, d, 64));
      float mn = fmaxf(mrow[j], vmax);
      sf[j] = __expf(mrow[j] - mn);
      mrow[j] = mn;
      float sum = 0.f;
#pragma unroll
      for (int f = 0; f < 4; ++f) {
        float e = __expf(tv[f][j] - mn);
        pv[f][j] = e;
        sum += e;
      }
#pragma unroll
      for (int d = 1; d < 16; d <<= 1) sum += __shfl_xor(sum, d, 64);
      lrow[j] = lrow[j] * sf[j] + sum;
    }
#pragma unroll
    for (int dn = 0; dn < 2; ++dn)
#pragma unroll
      for (int j = 0; j < 4; ++j) o[dn][j] *= sf[j];

    // P: C-layout -> LDS -> A-layout (per-wave region, in-order DS ops)
#pragma unroll
    for (int f = 0; f < 4; ++f)
#pragma unroll
      for (int j = 0; j < 4; ++j)
        pl[(lg * 4 + j) * 64 + f * 16 + lr] = f2bf(pv[f][j]);
    asm volatile("s_waitcnt lgkmcnt(0)" ::: "memory");
    __builtin_amdgcn_sched_barrier(0);   // rule #18: keep dependent reads below the wait
    bf16x8 pa0 = *(const bf16x8*)&pl[lr * 64 + lg * 8];
    bf16x8 pa1 = *(const bf16x8*)&pl[lr * 64 + 32 + lg * 8];
#pragma unroll
    for (int dn = 0; dn < 2; ++dn) {
      bf16x8 bv0 = *(const bf16x8*)&vb[((n << 8) + (h << 5) + dn * 16 + lr) * 1024 + (kt << 6) + lg * 8];
      o[dn] = __builtin_amdgcn_mfma_f32_16x16x32_bf16(pa0, bv0, o[dn], 0, 0, 0);
      bf16x8 bv1 = *(const bf16x8*)&vb[((n << 8) + (h << 5) + dn * 16 + lr) * 1024 + (kt << 6) + 32 + lg * 8];
      o[dn] = __builtin_amdgcn_mfma_f32_16x16x32_bf16(pa1, bv1, o[dn], 0, 0, 0);
    }
  }
#pragma unroll
  for (int dn = 0; dn < 2; ++dn)
#pragma unroll
    for (int j = 0; j < 4; ++j) {
      int q = qbase + lg * 4 + j;
      int d = dn * 16 + lr;
      float v = o[dn][j] / lrow[j];
      // reference reshape: attn_maps[n][h*32+(q>>5)][y=q&31][x=d]; AMT[ns][c] (B^T for 1x1 GEMM)
      AMT[((n << 10) + ((q & 31) << 5) + d) * 256 + (h << 5) + (q >> 5)] = f2bf(v);
    }
}

// ---------------- generic 128x128 GEMM core (C = A * B^T), single-buffer ----------------
static __device__ __forceinline__ void gemm_core(const u16* __restrict__ A,
                                                 const u16* __restrict__ B, int K,
                                                 u16* As, u16* Bs, f32x4 acc[4][4]) {
  const int tid = threadIdx.x;
  const int wave = tid >> 6, lane = tid & 63;
  const int wr = wave >> 1, wc = wave & 1;
  const int lr = lane & 15, lk = lane >> 4;
  const int srow = lane >> 3;
  const int scol = (lane & 7) << 3;
  const int bm = blockIdx.x, bn = blockIdx.y;
  for (int k0 = 0; k0 < K; k0 += 64) {
#pragma unroll
    for (int i = 0; i < 4; ++i) {
      int seg = i * 4 + wave;
      GLD(A + (bm * 128 + seg * 8 + srow) * K + k0 + scol, As + seg * 512);
      GLD(B + (bn * 128 + seg * 8 + srow) * K + k0 + scol, Bs + seg * 512);
    }
    __syncthreads();
#pragma unroll
    for (int kk = 0; kk < 2; ++kk) {
      bf16x8 af[4], bv[4];
#pragma unroll
      for (int m = 0; m < 4; ++m)
        af[m] = *(const bf16x8*)&As[(wr * 64 + m * 16 + lr) * 64 + kk * 32 + lk * 8];
#pragma unroll
      for (int n = 0; n < 4; ++n)
        bv[n] = *(const bf16x8*)&Bs[(wc * 64 + n * 16 + lr) * 64 + kk * 32 + lk * 8];
#pragma unroll
      for (int m = 0; m < 4; ++m)
#pragma unroll
        for (int n = 0; n < 4; ++n)
          acc[m][n] = __builtin_amdgcn_mfma_f32_16x16x32_bf16(af[m], bv[n], acc[m][n], 0, 0, 0);
    }
    __syncthreads();
  }
}

// ---------------- 1x1 conv GEMM: M=256, N=8192, K=256 -> out channels 256..511 ----------------
__global__ __launch_bounds__(256) void k_gemm_out(
    const u16* __restrict__ A, const u16* __restrict__ B, float* __restrict__ out,
    const float* __restrict__ attn_b) {
  __shared__ u16 As[8192], Bs[8192];
  f32x4 acc[4][4] = {};
  gemm_core(A, B, 256, As, Bs, acc);
  const int tid = threadIdx.x;
  const int wave = tid >> 6, lane = tid & 63;
  const int wr = wave >> 1, wc = wave & 1;
  const int lr = lane & 15, lk = lane >> 4;
  const int row0 = blockIdx.x * 128 + wr * 64 + lk * 4;
  const int col0 = blockIdx.y * 128 + wc * 64 + lr;
#pragma unroll
  for (int m = 0; m < 4; ++m) {
#pragma unroll
    for (int n = 0; n < 4; ++n) {
      int col = col0 + n * 16;
      int nn = col >> 10, s = col & 1023;
#pragma unroll
      for (int j = 0; j < 4; ++j) {
        int c = row0 + m * 16 + j;
        out[((nn << 9) + 256 + c) * 1024 + s] = acc[m][n][j] + attn_b[c];
      }
    }
  }
}

extern "C" void kernel_launch(void* const* d_in, const int* in_sizes, int n_in,
                              void* d_out, int out_size, void* d_ws, size_t ws_size,
                              hipStream_t stream) {
  const float* x      = (const float*)d_in[0];
  const float* conv_w = (const float*)d_in[1];
  const float* conv_b = (const float*)d_in[2];
  const float* q_w    = (const float*)d_in[3];
  const float* q_b    = (const float*)d_in[4];
  const float* k_w    = (const float*)d_in[5];
  const float* k_b    = (const float*)d_in[6];
  const float* v_w    = (const float*)d_in[7];
  const float* v_b    = (const float*)d_in[8];
  const float* attn_w = (const float*)d_in[9];
  const float* attn_b = (const float*)d_in[10];
  const float* wm     = (const float*)d_in[11];
  const float* hm     = (const float*)d_in[12];
  float* out = (float*)d_out;
  char* ws = (char*)d_ws;

  // workspace layout (bytes), total ~42.6 MB
  u16*   W9   = (u16*)(ws + 0);         // 1024*2304*2 = 4,718,592
  u16*   W1   = (u16*)(ws + 4718592);   //  256*256*2  =   131,072
  u16*   xT   = (u16*)(ws + 4849664);   // 8192*256*2  = 4,194,304
  u16*   zpg  = (u16*)(ws + 9043968);   // 512*2       =     1,024
  u16*   qbf  = (u16*)(ws + 9044992);   // 64*1024*32*2= 4,194,304
  u16*   kbf  = (u16*)(ws + 13239296);  //               4,194,304
  u16*   vbf  = (u16*)(ws + 17433600);  //               4,194,304
  float* Bw   = (float*)(ws + 21627904);// 2M*4 =        8,388,608
  float* Bh   = (float*)(ws + 30016512);//               8,388,608
  u16*   AMT  = (u16*)(ws + 38405120);  // 8192*256*2 =  4,194,304

  hipLaunchKernelGGL(k_cast_w, dim3(1024), dim3(256), 0, stream,
                     conv_w, q_w, k_w, v_w, attn_w, W9, W1);
  hipLaunchKernelGGL(k_xT, dim3(2048), dim3(256), 0, stream, x, xT, zpg);
  hipLaunchKernelGGL(k_gemm_conv, dim3(8, 64), dim3(512), 0, stream,
                     W9, xT, zpg, out, qbf, kbf, vbf, conv_b, q_b, k_b, v_b);
  hipLaunchKernelGGL(k_bias, dim3(256), dim3(256), 0, stream, qbf, wm, hm, Bw, Bh);
  hipLaunchKernelGGL(k_attn, dim3(1024), dim3(256), 0, stream, qbf, kbf, vbf, Bw, Bh, AMT);
  hipLaunchKernelGGL(k_gemm_out, dim3(2, 64), dim3(256), 0, stream, W1, AMT, out, attn_b);
}

// Round 7
// 285.931 us; speedup vs baseline: 1.0405x; 1.0294x over previous
//
#include <hip/hip_runtime.h>
#include <hip/hip_bf16.h>

// AAConv2d: N=8, CIN=256, COUT=512, HEADS=8, DK=DV=256, MAP=32, KS=3, PAD=1
// DKH=DVH=32, CONV_OUT=256, HW=1024, K_conv = 9*256 = 2304 (order: t9=ky*3+kx major, c minor)

typedef __attribute__((ext_vector_type(8))) __bf16 bf16x8;
typedef __attribute__((ext_vector_type(4))) float f32x4;
typedef unsigned short u16;
typedef unsigned int u32;
typedef __attribute__((ext_vector_type(8))) u16 u16x8;

#define GLD(gp, lp) __builtin_amdgcn_global_load_lds( \
    (const __attribute__((address_space(1))) u32*)(gp), \
    (__attribute__((address_space(3))) u32*)(lp), 16, 0, 0)

static __device__ __forceinline__ u16 f2bf(float f) {
  u32 u = __builtin_bit_cast(u32, f);
  u += 0x7fffu + ((u >> 16) & 1u);   // round-to-nearest-even
  return (u16)(u >> 16);
}
static __device__ __forceinline__ float bf2f(u16 h) {
  return __builtin_bit_cast(float, (u32)h << 16);
}

// ---------------- cast + reorder weights to bf16 (coalesced) ----------------
__global__ __launch_bounds__(256) void k_cast_w(
    const float* __restrict__ conv_w, const float* __restrict__ q_w,
    const float* __restrict__ k_w, const float* __restrict__ v_w,
    const float* __restrict__ attn_w, u16* __restrict__ W9, u16* __restrict__ W1) {
  __shared__ float t[2304];
  int row = blockIdx.x;
  const float* src = row < 256 ? conv_w : row < 512 ? q_w : row < 768 ? k_w : v_w;
  const float* sr = src + (row & 255) * 2304;
#pragma unroll
  for (int i = threadIdx.x; i < 2304; i += 256) t[i] = sr[i];   // coalesced [c][t9]
  __syncthreads();
  u16* dr = W9 + row * 2304;
#pragma unroll
  for (int i = threadIdx.x; i < 2304; i += 256) {
    int t9 = i >> 8, c = i & 255;
    dr[i] = f2bf(t[c * 9 + t9]);
  }
  if (row < 256) W1[row * 256 + threadIdx.x] = f2bf(attn_w[row * 256 + threadIdx.x]);
}

// ---------------- x transpose: xT[n][s=y*32+x][c] bf16, + zero page ----------------
__global__ void k_xT(const float* __restrict__ x, u16* __restrict__ xT,
                     u16* __restrict__ zpage) {
  if (blockIdx.x == 0 && threadIdx.x < 512) zpage[threadIdx.x] = 0;
  __shared__ float t[32][33];
  int b = blockIdx.x;                       // 2048 blocks: n(8) x cb(8) x sb(32)
  int sb = b & 31, cb = (b >> 5) & 7, n = b >> 8;
  int s0 = sb << 5, c0 = cb << 5;
  int ls = threadIdx.x & 31, lc = threadIdx.x >> 5;  // lc 0..7
#pragma unroll
  for (int i = 0; i < 4; ++i) {
    int c = lc + i * 8;
    t[c][ls] = x[(((n << 8) + c0 + c) << 10) + s0 + ls];
  }
  __syncthreads();
#pragma unroll
  for (int i = 0; i < 4; ++i) {
    int s = lc + i * 8;
    xT[(((n << 10) + s0 + s) << 8) + c0 + ls] = f2bf(t[ls][s]);
  }
}

// ---------------- implicit conv GEMM, counted-vmcnt pipeline ----------------
// M=1024 (co) x N=8192 (ns) x K=2304. BM=256, BN=128, BK=64, 8 waves (4M x 2N of 64x64).
// A = W9; B[ns][t9*256+c] = xT[n][s+dy*32+dx][c] (0 at borders) via per-lane src addr.
// T2 both-sides swizzle: linear GLD dest + inverse-swizzled GLOBAL src col + swizzled ds_read.
// T3/T4: double-buffer, s_waitcnt vmcnt(6) (never 0 in loop), raw barriers. T5: setprio.
__global__ __launch_bounds__(512) void k_gemm_conv(
    const u16* __restrict__ A, const u16* __restrict__ xT, const u16* __restrict__ zpage,
    float* __restrict__ out,
    u16* __restrict__ qb, u16* __restrict__ kb, u16* __restrict__ vb,
    const float* __restrict__ conv_b, const float* __restrict__ q_b,
    const float* __restrict__ k_b, const float* __restrict__ v_b) {
  __shared__ u16 As[2][16384];   // 64 KB: 256 rows x 64
  __shared__ u16 Bs[2][8192];    // 32 KB: 128 rows x 64
  f32x4 acc[4][4] = {};
  const int tid = threadIdx.x;
  const int wave = tid >> 6, lane = tid & 63;
  const int wr = wave >> 1, wc = wave & 1;       // wave grid 4 (M) x 2 (N)
  const int lr = lane & 15, lk = lane >> 4;
  const int srow = lane >> 3;                    // staging row within 8-row group
  const int swz = 8 * ((lane & 7) ^ (srow & 7)); // inverse-swizzled source col (elems)
  const int bm = blockIdx.x, bn = blockIdx.y;

  // per-lane B-row geometry (constant over K): 2 issues/wave, rows r*64 + wave*8 + srow
  int bn_y[2], bn_x[2], bn_base[2];
#pragma unroll
  for (int r = 0; r < 2; ++r) {
    int col = bn * 128 + r * 64 + wave * 8 + srow;   // ns
    int n = col >> 10, s = col & 1023;
    bn_y[r] = s >> 5;
    bn_x[r] = s & 31;
    bn_base[r] = n << 10;
  }
  // A source rows (constant over K): 4 issues
  const u16* a_src[4];
#pragma unroll
  for (int a = 0; a < 4; ++a)
    a_src[a] = A + (bm * 256 + a * 64 + wave * 8 + srow) * 2304 + swz;

  auto stage = [&](int buf, int t) {
    int k0 = t << 6;
    int t9 = k0 >> 8;
    int dy = t9 / 3 - 1, dx = t9 - (t9 / 3) * 3 - 1;
    int c0 = k0 & 255;
#pragma unroll
    for (int a = 0; a < 4; ++a)
      GLD(a_src[a] + k0, &As[buf][a * 4096 + wave * 512]);
#pragma unroll
    for (int r = 0; r < 2; ++r) {
      int sy = bn_y[r] + dy, sx = bn_x[r] + dx;
      bool ok = ((u32)sy < 32u) && ((u32)sx < 32u);
      const u16* src = ok ? (xT + ((bn_base[r] + (sy << 5) + sx) << 8) + c0 + swz)
                          : (zpage + swz);
      GLD(src, &Bs[buf][r * 4096 + wave * 512]);
    }
  };

  // swizzled ds_read element offsets (within a 64-elem row): ((kk*4+lk)^(lr&7))*8
  const int rswz = lr & 7;
  const int arow = (wr * 64 + lr) * 64;   // + m*16*64
  const int brow = (wc * 64 + lr) * 64;   // + n*16*64

  auto compute = [&](int buf) {
#pragma unroll
    for (int kk = 0; kk < 2; ++kk) {
      const int cswz = (((kk << 2) | lk) ^ rswz) << 3;
      bf16x8 af[4], bv[4];
#pragma unroll
      for (int m = 0; m < 4; ++m)
        af[m] = *(const bf16x8*)&As[buf][arow + m * 1024 + cswz];
#pragma unroll
      for (int n = 0; n < 4; ++n)
        bv[n] = *(const bf16x8*)&Bs[buf][brow + n * 1024 + cswz];
      __builtin_amdgcn_s_setprio(1);
#pragma unroll
      for (int m = 0; m < 4; ++m)
#pragma unroll
        for (int n = 0; n < 4; ++n)
          acc[m][n] = __builtin_amdgcn_mfma_f32_16x16x32_bf16(af[m], bv[n], acc[m][n], 0, 0, 0);
      __builtin_amdgcn_s_setprio(0);
    }
  };

  stage(0, 0);
  stage(1, 1);
  for (int t = 0; t < 35; ++t) {
    asm volatile("s_waitcnt vmcnt(6)" ::: "memory");   // tile t landed; t+1 stays in flight
    __builtin_amdgcn_s_barrier();
    compute(t & 1);
    __builtin_amdgcn_s_barrier();                      // all waves done reading buf t&1
    if (t + 2 < 36) stage(t & 1, t + 2);
  }
  asm volatile("s_waitcnt vmcnt(0)" ::: "memory");     // final tile drain
  __builtin_amdgcn_s_barrier();
  compute(35 & 1);

  const int row0 = bm * 256 + wr * 64 + lk * 4;  // C/D: row=(lane>>4)*4+j
  const int col0 = bn * 128 + wc * 64 + lr;      // C/D: col=lane&15
#pragma unroll
  for (int m = 0; m < 4; ++m) {
#pragma unroll
    for (int n = 0; n < 4; ++n) {
      int col = col0 + n * 16;
      int nn = col >> 10, s = col & 1023;
#pragma unroll
      for (int j = 0; j < 4; ++j) {
        int c = row0 + m * 16 + j;
        float v = acc[m][n][j];
        if (c < 256) {
          out[((nn << 9) + c) * 1024 + s] = v + conv_b[c];
        } else if (c < 512) {
          int cc = c - 256;
          qb[((((nn << 3) + (cc >> 5)) << 10) + s) * 32 + (cc & 31)] = f2bf(v + q_b[cc]);
        } else if (c < 768) {
          int cc = c - 512;
          kb[((((nn << 3) + (cc >> 5)) << 10) + s) * 32 + (cc & 31)] = f2bf(v + k_b[cc]);
        } else {
          int cc = c - 768;
          vb[((nn << 8) + cc) * 1024 + s] = f2bf(v + v_b[cc]);
        }
      }
    }
  }
}

// ---------------- rel-position bias tables ----------------
__global__ __launch_bounds__(256) void k_bias(const u16* __restrict__ qb,
                                              const float* __restrict__ wm,
                                              const float* __restrict__ hm,
                                              float* __restrict__ Bw, float* __restrict__ Bh) {
  int pos = blockIdx.x * blockDim.x + threadIdx.x;  // 65536
  int s = pos & 1023;
  int y = s >> 5, xx = s & 31;
  float q[32];
  const u16x8* q8 = (const u16x8*)(qb + pos * 32);
#pragma unroll
  for (int v = 0; v < 4; ++v) {
    u16x8 w = q8[v];
#pragma unroll
    for (int e = 0; e < 8; ++e) q[v * 8 + e] = bf2f(w[e]);
  }
  float* bwo = Bw + pos * 32;
  float* bho = Bh + pos * 32;
#pragma unroll 4
  for (int r = 0; r < 32; ++r) {
    const f32x4* wr = (const f32x4*)(wm + (r - xx + 31) * 32);
    const f32x4* hr = (const f32x4*)(hm + (r - y + 31) * 32);
    float aw = 0.f, ah = 0.f;
#pragma unroll
    for (int i = 0; i < 8; ++i) {
      f32x4 wv = wr[i], hv = hr[i];
#pragma unroll
      for (int e = 0; e < 4; ++e) {
        float qd = q[i * 4 + e];
        aw += qd * wv[e];
        ah += qd * hv[e];
      }
    }
    bwo[r] = aw;
    bho[r] = ah;
  }
}

// ---------------- flash attention with rel-pos bias ----------------
__global__ __launch_bounds__(256) void k_attn(
    const u16* __restrict__ qb, const u16* __restrict__ kb, const u16* __restrict__ vb,
    const float* __restrict__ Bw, const float* __restrict__ Bh, u16* __restrict__ AMT) {
  __shared__ u16 Pl[4][1024];  // per-wave P tile 16x64
  const int wave = threadIdx.x >> 6, lane = threadIdx.x & 63;
  const int task = blockIdx.x * 4 + wave;  // 4096 tasks = 64 nh * 64 q-groups
  const int nh = task >> 6, qg = task & 63;
  const int n = nh >> 3, h = nh & 7;
  const int qbase = qg << 4;
  const int lr = lane & 15, lg = lane >> 4;

  bf16x8 aq = *(const bf16x8*)&qb[((nh << 10) + qbase + lr) * 32 + lg * 8];

  float Bwr[2][4];
#pragma unroll
  for (int p = 0; p < 2; ++p)
#pragma unroll
    for (int j = 0; j < 4; ++j)
      Bwr[p][j] = Bw[((nh << 10) + qbase + lg * 4 + j) * 32 + p * 16 + lr];

  float mrow[4] = {-1e30f, -1e30f, -1e30f, -1e30f};
  float lrow[4] = {0.f, 0.f, 0.f, 0.f};
  f32x4 o[2] = {};
  u16* pl = Pl[wave];

  for (int kt = 0; kt < 16; ++kt) {
    f32x4 zero = {0.f, 0.f, 0.f, 0.f};
    f32x4 sf_[4];
#pragma unroll
    for (int f = 0; f < 4; ++f) {
      bf16x8 bk = *(const bf16x8*)&kb[((nh << 10) + (kt << 6) + f * 16 + lr) * 32 + lg * 8];
      sf_[f] = __builtin_amdgcn_mfma_f32_16x16x32_bf16(aq, bk, zero, 0, 0, 0);
    }
    float Bhr[2][4];  // ky = kt*2 + p
#pragma unroll
    for (int p = 0; p < 2; ++p)
#pragma unroll
      for (int j = 0; j < 4; ++j)
        Bhr[p][j] = Bh[((nh << 10) + qbase + lg * 4 + j) * 32 + (kt << 1) + p];
    float tv[4][4];
#pragma unroll
    for (int f = 0; f < 4; ++f)   // k col = f*16+lr -> kx=(f&1)*16+lr, ky_local=f>>1
#pragma unroll
      for (int j = 0; j < 4; ++j)
        tv[f][j] = (sf_[f][j] + Bhr[f >> 1][j] + Bwr[f & 1][j]) * 0.17677669529663687f;

    float pv[4][4], sf[4];
#pragma unroll
    for (int j = 0; j < 4; ++j) {
      float vmax = fmaxf(fmaxf(tv[0][j], tv[1][j]), fmaxf(tv[2][j], tv[3][j]));
#pragma unroll
      for (int d = 1; d < 16; d <<= 1) vmax = fmaxf(vmax, __shfl_xor(vmax, d, 64));
      float mn = fmaxf(mrow[j], vmax);
      sf[j] = __expf(mrow[j] - mn);
      mrow[j] = mn;
      float sum = 0.f;
#pragma unroll
      for (int f = 0; f < 4; ++f) {
        float e = __expf(tv[f][j] - mn);
        pv[f][j] = e;
        sum += e;
      }
#pragma unroll
      for (int d = 1; d < 16; d <<= 1) sum += __shfl_xor(sum, d, 64);
      lrow[j] = lrow[j] * sf[j] + sum;
    }
#pragma unroll
    for (int dn = 0; dn < 2; ++dn)
#pragma unroll
      for (int j = 0; j < 4; ++j) o[dn][j] *= sf[j];

#pragma unroll
    for (int f = 0; f < 4; ++f)
#pragma unroll
      for (int j = 0; j < 4; ++j)
        pl[(lg * 4 + j) * 64 + f * 16 + lr] = f2bf(pv[f][j]);
    asm volatile("s_waitcnt lgkmcnt(0)" ::: "memory");
    __builtin_amdgcn_sched_barrier(0);   // rule #18
    bf16x8 pa0 = *(const bf16x8*)&pl[lr * 64 + lg * 8];
    bf16x8 pa1 = *(const bf16x8*)&pl[lr * 64 + 32 + lg * 8];
#pragma unroll
    for (int dn = 0; dn < 2; ++dn) {
      bf16x8 bv0 = *(const bf16x8*)&vb[((n << 8) + (h << 5) + dn * 16 + lr) * 1024 + (kt << 6) + lg * 8];
      o[dn] = __builtin_amdgcn_mfma_f32_16x16x32_bf16(pa0, bv0, o[dn], 0, 0, 0);
      bf16x8 bv1 = *(const bf16x8*)&vb[((n << 8) + (h << 5) + dn * 16 + lr) * 1024 + (kt << 6) + 32 + lg * 8];
      o[dn] = __builtin_amdgcn_mfma_f32_16x16x32_bf16(pa1, bv1, o[dn], 0, 0, 0);
    }
  }
#pragma unroll
  for (int dn = 0; dn < 2; ++dn)
#pragma unroll
    for (int j = 0; j < 4; ++j) {
      int q = qbase + lg * 4 + j;
      int d = dn * 16 + lr;
      float v = o[dn][j] / lrow[j];
      AMT[((n << 10) + ((q & 31) << 5) + d) * 256 + (h << 5) + (q >> 5)] = f2bf(v);
    }
}

// ---------------- generic 128x128 GEMM core (C = A * B^T), single-buffer ----------------
static __device__ __forceinline__ void gemm_core(const u16* __restrict__ A,
                                                 const u16* __restrict__ B, int K,
                                                 u16* As, u16* Bs, f32x4 acc[4][4]) {
  const int tid = threadIdx.x;
  const int wave = tid >> 6, lane = tid & 63;
  const int wr = wave >> 1, wc = wave & 1;
  const int lr = lane & 15, lk = lane >> 4;
  const int srow = lane >> 3;
  const int scol = (lane & 7) << 3;
  const int bm = blockIdx.x, bn = blockIdx.y;
  for (int k0 = 0; k0 < K; k0 += 64) {
#pragma unroll
    for (int i = 0; i < 4; ++i) {
      int seg = i * 4 + wave;
      GLD(A + (bm * 128 + seg * 8 + srow) * K + k0 + scol, As + seg * 512);
      GLD(B + (bn * 128 + seg * 8 + srow) * K + k0 + scol, Bs + seg * 512);
    }
    __syncthreads();
#pragma unroll
    for (int kk = 0; kk < 2; ++kk) {
      bf16x8 af[4], bv[4];
#pragma unroll
      for (int m = 0; m < 4; ++m)
        af[m] = *(const bf16x8*)&As[(wr * 64 + m * 16 + lr) * 64 + kk * 32 + lk * 8];
#pragma unroll
      for (int n = 0; n < 4; ++n)
        bv[n] = *(const bf16x8*)&Bs[(wc * 64 + n * 16 + lr) * 64 + kk * 32 + lk * 8];
#pragma unroll
      for (int m = 0; m < 4; ++m)
#pragma unroll
        for (int n = 0; n < 4; ++n)
          acc[m][n] = __builtin_amdgcn_mfma_f32_16x16x32_bf16(af[m], bv[n], acc[m][n], 0, 0, 0);
    }
    __syncthreads();
  }
}

// ---------------- 1x1 conv GEMM: M=256, N=8192, K=256 -> out channels 256..511 ----------------
__global__ __launch_bounds__(256) void k_gemm_out(
    const u16* __restrict__ A, const u16* __restrict__ B, float* __restrict__ out,
    const float* __restrict__ attn_b) {
  __shared__ u16 As[8192], Bs[8192];
  f32x4 acc[4][4] = {};
  gemm_core(A, B, 256, As, Bs, acc);
  const int tid = threadIdx.x;
  const int wave = tid >> 6, lane = tid & 63;
  const int wr = wave >> 1, wc = wave & 1;
  const int lr = lane & 15, lk = lane >> 4;
  const int row0 = blockIdx.x * 128 + wr * 64 + lk * 4;
  const int col0 = blockIdx.y * 128 + wc * 64 + lr;
#pragma unroll
  for (int m = 0; m < 4; ++m) {
#pragma unroll
    for (int n = 0; n < 4; ++n) {
      int col = col0 + n * 16;
      int nn = col >> 10, s = col & 1023;
#pragma unroll
      for (int j = 0; j < 4; ++j) {
        int c = row0 + m * 16 + j;
        out[((nn << 9) + 256 + c) * 1024 + s] = acc[m][n][j] + attn_b[c];
      }
    }
  }
}

extern "C" void kernel_launch(void* const* d_in, const int* in_sizes, int n_in,
                              void* d_out, int out_size, void* d_ws, size_t ws_size,
                              hipStream_t stream) {
  const float* x      = (const float*)d_in[0];
  const float* conv_w = (const float*)d_in[1];
  const float* conv_b = (const float*)d_in[2];
  const float* q_w    = (const float*)d_in[3];
  const float* q_b    = (const float*)d_in[4];
  const float* k_w    = (const float*)d_in[5];
  const float* k_b    = (const float*)d_in[6];
  const float* v_w    = (const float*)d_in[7];
  const float* v_b    = (const float*)d_in[8];
  const float* attn_w = (const float*)d_in[9];
  const float* attn_b = (const float*)d_in[10];
  const float* wm     = (const float*)d_in[11];
  const float* hm     = (const float*)d_in[12];
  float* out = (float*)d_out;
  char* ws = (char*)d_ws;

  // workspace layout (bytes), total ~42.6 MB
  u16*   W9   = (u16*)(ws + 0);         // 1024*2304*2 = 4,718,592
  u16*   W1   = (u16*)(ws + 4718592);   //  256*256*2  =   131,072
  u16*   xT   = (u16*)(ws + 4849664);   // 8192*256*2  = 4,194,304
  u16*   zpg  = (u16*)(ws + 9043968);   // 512*2       =     1,024
  u16*   qbf  = (u16*)(ws + 9044992);   // 64*1024*32*2= 4,194,304
  u16*   kbf  = (u16*)(ws + 13239296);  //               4,194,304
  u16*   vbf  = (u16*)(ws + 17433600);  //               4,194,304
  float* Bw   = (float*)(ws + 21627904);// 2M*4 =        8,388,608
  float* Bh   = (float*)(ws + 30016512);//               8,388,608
  u16*   AMT  = (u16*)(ws + 38405120);  // 8192*256*2 =  4,194,304

  hipLaunchKernelGGL(k_cast_w, dim3(1024), dim3(256), 0, stream,
                     conv_w, q_w, k_w, v_w, attn_w, W9, W1);
  hipLaunchKernelGGL(k_xT, dim3(2048), dim3(256), 0, stream, x, xT, zpg);
  hipLaunchKernelGGL(k_gemm_conv, dim3(4, 64), dim3(512), 0, stream,
                     W9, xT, zpg, out, qbf, kbf, vbf, conv_b, q_b, k_b, v_b);
  hipLaunchKernelGGL(k_bias, dim3(256), dim3(256), 0, stream, qbf, wm, hm, Bw, Bh);
  hipLaunchKernelGGL(k_attn, dim3(1024), dim3(256), 0, stream, qbf, kbf, vbf, Bw, Bh, AMT);
  hipLaunchKernelGGL(k_gemm_out, dim3(2, 64), dim3(256), 0, stream, W1, AMT, out, attn_b);
}

// Round 9
// 253.318 us; speedup vs baseline: 1.1745x; 1.1287x over previous
//
#include <hip/hip_runtime.h>
#include <hip/hip_bf16.h>

// AAConv2d: N=8, CIN=256, COUT=512, HEADS=8, DK=DV=256, MAP=32, KS=3, PAD=1
// DKH=DVH=32, CONV_OUT=256, HW=1024, K_conv = 9*256 = 2304 (order: t9=ky*3+kx major, c minor)

typedef __attribute__((ext_vector_type(8))) __bf16 bf16x8;
typedef __attribute__((ext_vector_type(4))) float f32x4;
typedef unsigned short u16;
typedef unsigned int u32;
typedef __attribute__((ext_vector_type(8))) u16 u16x8;

#define GLD(gp, lp) __builtin_amdgcn_global_load_lds( \
    (const __attribute__((address_space(1))) u32*)(gp), \
    (__attribute__((address_space(3))) u32*)(lp), 16, 0, 0)

static __device__ __forceinline__ u16 f2bf(float f) {
  u32 u = __builtin_bit_cast(u32, f);
  u += 0x7fffu + ((u >> 16) & 1u);   // round-to-nearest-even
  return (u16)(u >> 16);
}
static __device__ __forceinline__ float bf2f(u16 h) {
  return __builtin_bit_cast(float, (u32)h << 16);
}

// ---------------- cast + reorder weights to bf16 (coalesced) ----------------
__global__ __launch_bounds__(256) void k_cast_w(
    const float* __restrict__ conv_w, const float* __restrict__ q_w,
    const float* __restrict__ k_w, const float* __restrict__ v_w,
    const float* __restrict__ attn_w, u16* __restrict__ W9, u16* __restrict__ W1) {
  __shared__ float t[2304];
  int row = blockIdx.x;
  const float* src = row < 256 ? conv_w : row < 512 ? q_w : row < 768 ? k_w : v_w;
  const float* sr = src + (row & 255) * 2304;
#pragma unroll
  for (int i = threadIdx.x; i < 2304; i += 256) t[i] = sr[i];   // coalesced [c][t9]
  __syncthreads();
  u16* dr = W9 + row * 2304;
#pragma unroll
  for (int i = threadIdx.x; i < 2304; i += 256) {
    int t9 = i >> 8, c = i & 255;
    dr[i] = f2bf(t[c * 9 + t9]);
  }
  if (row < 256) W1[row * 256 + threadIdx.x] = f2bf(attn_w[row * 256 + threadIdx.x]);
}

// ---------------- x transpose: xT[n][s=y*32+x][c] bf16, + zero page ----------------
__global__ void k_xT(const float* __restrict__ x, u16* __restrict__ xT,
                     u16* __restrict__ zpage) {
  if (blockIdx.x == 0 && threadIdx.x < 512) zpage[threadIdx.x] = 0;
  __shared__ float t[32][33];
  int b = blockIdx.x;                       // 2048 blocks: n(8) x cb(8) x sb(32)
  int sb = b & 31, cb = (b >> 5) & 7, n = b >> 8;
  int s0 = sb << 5, c0 = cb << 5;
  int ls = threadIdx.x & 31, lc = threadIdx.x >> 5;  // lc 0..7
#pragma unroll
  for (int i = 0; i < 4; ++i) {
    int c = lc + i * 8;
    t[c][ls] = x[(((n << 8) + c0 + c) << 10) + s0 + ls];
  }
  __syncthreads();
#pragma unroll
  for (int i = 0; i < 4; ++i) {
    int s = lc + i * 8;
    xT[(((n << 10) + s0 + s) << 8) + c0 + ls] = f2bf(t[ls][s]);
  }
}

// ---------------- implicit conv GEMM, counted-vmcnt pipeline (R7-verified) ----------------
__global__ __launch_bounds__(512) void k_gemm_conv(
    const u16* __restrict__ A, const u16* __restrict__ xT, const u16* __restrict__ zpage,
    float* __restrict__ out,
    u16* __restrict__ qb, u16* __restrict__ kb, u16* __restrict__ vb,
    const float* __restrict__ conv_b, const float* __restrict__ q_b,
    const float* __restrict__ k_b, const float* __restrict__ v_b) {
  __shared__ u16 As[2][16384];   // 64 KB: 256 rows x 64
  __shared__ u16 Bs[2][8192];    // 32 KB: 128 rows x 64
  f32x4 acc[4][4] = {};
  const int tid = threadIdx.x;
  const int wave = tid >> 6, lane = tid & 63;
  const int wr = wave >> 1, wc = wave & 1;       // wave grid 4 (M) x 2 (N)
  const int lr = lane & 15, lk = lane >> 4;
  const int srow = lane >> 3;                    // staging row within 8-row group
  const int swz = 8 * ((lane & 7) ^ (srow & 7)); // inverse-swizzled source col (elems)
  const int bm = blockIdx.x, bn = blockIdx.y;

  int bn_y[2], bn_x[2], bn_base[2];
#pragma unroll
  for (int r = 0; r < 2; ++r) {
    int col = bn * 128 + r * 64 + wave * 8 + srow;   // ns
    int n = col >> 10, s = col & 1023;
    bn_y[r] = s >> 5;
    bn_x[r] = s & 31;
    bn_base[r] = n << 10;
  }
  const u16* a_src[4];
#pragma unroll
  for (int a = 0; a < 4; ++a)
    a_src[a] = A + (bm * 256 + a * 64 + wave * 8 + srow) * 2304 + swz;

  auto stage = [&](int buf, int t) {
    int k0 = t << 6;
    int t9 = k0 >> 8;
    int dy = t9 / 3 - 1, dx = t9 - (t9 / 3) * 3 - 1;
    int c0 = k0 & 255;
#pragma unroll
    for (int a = 0; a < 4; ++a)
      GLD(a_src[a] + k0, &As[buf][a * 4096 + wave * 512]);
#pragma unroll
    for (int r = 0; r < 2; ++r) {
      int sy = bn_y[r] + dy, sx = bn_x[r] + dx;
      bool ok = ((u32)sy < 32u) && ((u32)sx < 32u);
      const u16* src = ok ? (xT + ((bn_base[r] + (sy << 5) + sx) << 8) + c0 + swz)
                          : (zpage + swz);
      GLD(src, &Bs[buf][r * 4096 + wave * 512]);
    }
  };

  const int rswz = lr & 7;
  const int arow = (wr * 64 + lr) * 64;
  const int brow = (wc * 64 + lr) * 64;

  auto compute = [&](int buf) {
#pragma unroll
    for (int kk = 0; kk < 2; ++kk) {
      const int cswz = (((kk << 2) | lk) ^ rswz) << 3;
      bf16x8 af[4], bv[4];
#pragma unroll
      for (int m = 0; m < 4; ++m)
        af[m] = *(const bf16x8*)&As[buf][arow + m * 1024 + cswz];
#pragma unroll
      for (int n = 0; n < 4; ++n)
        bv[n] = *(const bf16x8*)&Bs[buf][brow + n * 1024 + cswz];
      __builtin_amdgcn_s_setprio(1);
#pragma unroll
      for (int m = 0; m < 4; ++m)
#pragma unroll
        for (int n = 0; n < 4; ++n)
          acc[m][n] = __builtin_amdgcn_mfma_f32_16x16x32_bf16(af[m], bv[n], acc[m][n], 0, 0, 0);
      __builtin_amdgcn_s_setprio(0);
    }
  };

  stage(0, 0);
  stage(1, 1);
  for (int t = 0; t < 35; ++t) {
    asm volatile("s_waitcnt vmcnt(6)" ::: "memory");   // tile t landed; t+1 stays in flight
    __builtin_amdgcn_s_barrier();
    compute(t & 1);
    __builtin_amdgcn_s_barrier();                      // all waves done reading buf t&1
    if (t + 2 < 36) stage(t & 1, t + 2);
  }
  asm volatile("s_waitcnt vmcnt(0)" ::: "memory");     // final tile drain
  __builtin_amdgcn_s_barrier();
  compute(35 & 1);

  const int row0 = bm * 256 + wr * 64 + lk * 4;  // C/D: row=(lane>>4)*4+j
  const int col0 = bn * 128 + wc * 64 + lr;      // C/D: col=lane&15
#pragma unroll
  for (int m = 0; m < 4; ++m) {
#pragma unroll
    for (int n = 0; n < 4; ++n) {
      int col = col0 + n * 16;
      int nn = col >> 10, s = col & 1023;
#pragma unroll
      for (int j = 0; j < 4; ++j) {
        int c = row0 + m * 16 + j;
        float v = acc[m][n][j];
        if (c < 256) {
          out[((nn << 9) + c) * 1024 + s] = v + conv_b[c];
        } else if (c < 512) {
          int cc = c - 256;
          qb[((((nn << 3) + (cc >> 5)) << 10) + s) * 32 + (cc & 31)] = f2bf(v + q_b[cc]);
        } else if (c < 768) {
          int cc = c - 512;
          kb[((((nn << 3) + (cc >> 5)) << 10) + s) * 32 + (cc & 31)] = f2bf(v + k_b[cc]);
        } else {
          int cc = c - 768;
          vb[((nn << 8) + cc) * 1024 + s] = f2bf(v + v_b[cc]);
        }
      }
    }
  }
}

// ---------------- rel-position bias tables (LDS-staged wm/hm) ----------------
// one thread per pos: Bw[pos][r] = q(pos).wm[r-x+31], Bh[pos][r] = q(pos).hm[r-y+31]
__global__ __launch_bounds__(256) void k_bias(const u16* __restrict__ qb,
                                              const float* __restrict__ wm,
                                              const float* __restrict__ hm,
                                              float* __restrict__ Bw, float* __restrict__ Bh) {
  __shared__ float wl[63 * 36], hl[63 * 36];   // stride 36: 16B-aligned rows, bank-spread
  for (int i = threadIdx.x; i < 2016; i += 256) {
    int r = i >> 5, c = i & 31;
    wl[r * 36 + c] = wm[i];
    hl[r * 36 + c] = hm[i];
  }
  __syncthreads();
  int pos = blockIdx.x * blockDim.x + threadIdx.x;  // 65536
  int s = pos & 1023;
  int y = s >> 5, xx = s & 31;
  float q[32];
  const u16x8* q8 = (const u16x8*)(qb + pos * 32);
#pragma unroll
  for (int v = 0; v < 4; ++v) {
    u16x8 w = q8[v];
#pragma unroll
    for (int e = 0; e < 8; ++e) q[v * 8 + e] = bf2f(w[e]);
  }
  float* bwo = Bw + pos * 32;
  float* bho = Bh + pos * 32;
#pragma unroll 4
  for (int r = 0; r < 32; ++r) {
    const f32x4* wr = (const f32x4*)&wl[(r - xx + 31) * 36];
    const f32x4* hr = (const f32x4*)&hl[(r - y + 31) * 36];
    float aw = 0.f, ah = 0.f;
#pragma unroll
    for (int i = 0; i < 8; ++i) {
      f32x4 wv = wr[i], hv = hr[i];
#pragma unroll
      for (int e = 0; e < 4; ++e) {
        float qd = q[i * 4 + e];
        aw += qd * wv[e];
        ah += qd * hv[e];
      }
    }
    bwo[r] = aw;
    bho[r] = ah;
  }
}

// ---------------- flash attention with rel-pos bias ----------------
// P-tile LDS rows padded to 72 elems (144 B): write conflicts 8->4-way, read 16->~min.
__global__ __launch_bounds__(256) void k_attn(
    const u16* __restrict__ qb, const u16* __restrict__ kb, const u16* __restrict__ vb,
    const float* __restrict__ Bw, const float* __restrict__ Bh, u16* __restrict__ AMT) {
  __shared__ u16 Pl[4][16 * 72];  // per-wave P tile 16x64, stride 72
  const int wave = threadIdx.x >> 6, lane = threadIdx.x & 63;
  const int task = blockIdx.x * 4 + wave;  // 4096 tasks = 64 nh * 64 q-groups
  const int nh = task >> 6, qg = task & 63;
  const int n = nh >> 3, h = nh & 7;
  const int qbase = qg << 4;
  const int lr = lane & 15, lg = lane >> 4;

  bf16x8 aq = *(const bf16x8*)&qb[((nh << 10) + qbase + lr) * 32 + lg * 8];

  float Bwr[2][4];
#pragma unroll
  for (int p = 0; p < 2; ++p)
#pragma unroll
    for (int j = 0; j < 4; ++j)
      Bwr[p][j] = Bw[((nh << 10) + qbase + lg * 4 + j) * 32 + p * 16 + lr];

  float mrow[4] = {-1e30f, -1e30f, -1e30f, -1e30f};
  float lrow[4] = {0.f, 0.f, 0.f, 0.f};
  f32x4 o[2] = {};
  u16* pl = Pl[wave];

  for (int kt = 0; kt < 16; ++kt) {
    f32x4 zero = {0.f, 0.f, 0.f, 0.f};
    f32x4 sf_[4];
#pragma unroll
    for (int f = 0; f < 4; ++f) {
      bf16x8 bk = *(const bf16x8*)&kb[((nh << 10) + (kt << 6) + f * 16 + lr) * 32 + lg * 8];
      sf_[f] = __builtin_amdgcn_mfma_f32_16x16x32_bf16(aq, bk, zero, 0, 0, 0);
    }
    float Bhr[2][4];  // ky = kt*2 + p
#pragma unroll
    for (int p = 0; p < 2; ++p)
#pragma unroll
      for (int j = 0; j < 4; ++j)
        Bhr[p][j] = Bh[((nh << 10) + qbase + lg * 4 + j) * 32 + (kt << 1) + p];
    float tv[4][4];
#pragma unroll
    for (int f = 0; f < 4; ++f)   // k col = f*16+lr -> kx=(f&1)*16+lr, ky_local=f>>1
#pragma unroll
      for (int j = 0; j < 4; ++j)
        tv[f][j] = (sf_[f][j] + Bhr[f >> 1][j] + Bwr[f & 1][j]) * 0.17677669529663687f;

    float pv[4][4], sf[4];
#pragma unroll
    for (int j = 0; j < 4; ++j) {
      float vmax = fmaxf(fmaxf(tv[0][j], tv[1][j]), fmaxf(tv[2][j], tv[3][j]));
#pragma unroll
      for (int d = 1; d < 16; d <<= 1) vmax = fmaxf(vmax, __shfl_xor(vmax, d, 64));
      float mn = fmaxf(mrow[j], vmax);
      sf[j] = __expf(mrow[j] - mn);
      mrow[j] = mn;
      float sum = 0.f;
#pragma unroll
      for (int f = 0; f < 4; ++f) {
        float e = __expf(tv[f][j] - mn);
        pv[f][j] = e;
        sum += e;
      }
#pragma unroll
      for (int d = 1; d < 16; d <<= 1) sum += __shfl_xor(sum, d, 64);
      lrow[j] = lrow[j] * sf[j] + sum;
    }
#pragma unroll
    for (int dn = 0; dn < 2; ++dn)
#pragma unroll
      for (int j = 0; j < 4; ++j) o[dn][j] *= sf[j];

#pragma unroll
    for (int f = 0; f < 4; ++f)
#pragma unroll
      for (int j = 0; j < 4; ++j)
        pl[(lg * 4 + j) * 72 + f * 16 + lr] = f2bf(pv[f][j]);
    asm volatile("s_waitcnt lgkmcnt(0)" ::: "memory");
    __builtin_amdgcn_sched_barrier(0);   // rule #18
    bf16x8 pa0 = *(const bf16x8*)&pl[lr * 72 + lg * 8];
    bf16x8 pa1 = *(const bf16x8*)&pl[lr * 72 + 32 + lg * 8];
#pragma unroll
    for (int dn = 0; dn < 2; ++dn) {
      bf16x8 bv0 = *(const bf16x8*)&vb[((n << 8) + (h << 5) + dn * 16 + lr) * 1024 + (kt << 6) + lg * 8];
      o[dn] = __builtin_amdgcn_mfma_f32_16x16x32_bf16(pa0, bv0, o[dn], 0, 0, 0);
      bf16x8 bv1 = *(const bf16x8*)&vb[((n << 8) + (h << 5) + dn * 16 + lr) * 1024 + (kt << 6) + 32 + lg * 8];
      o[dn] = __builtin_amdgcn_mfma_f32_16x16x32_bf16(pa1, bv1, o[dn], 0, 0, 0);
    }
  }
#pragma unroll
  for (int dn = 0; dn < 2; ++dn)
#pragma unroll
    for (int j = 0; j < 4; ++j) {
      int q = qbase + lg * 4 + j;
      int d = dn * 16 + lr;
      float v = o[dn][j] / lrow[j];
      AMT[((n << 10) + ((q & 31) << 5) + d) * 256 + (h << 5) + (q >> 5)] = f2bf(v);
    }
}

// ---------------- generic 128x128 GEMM core (C = A * B^T), single-buffer ----------------
static __device__ __forceinline__ void gemm_core(const u16* __restrict__ A,
                                                 const u16* __restrict__ B, int K,
                                                 u16* As, u16* Bs, f32x4 acc[4][4]) {
  const int tid = threadIdx.x;
  const int wave = tid >> 6, lane = tid & 63;
  const int wr = wave >> 1, wc = wave & 1;
  const int lr = lane & 15, lk = lane >> 4;
  const int srow = lane >> 3;
  const int scol = (lane & 7) << 3;
  const int bm = blockIdx.x, bn = blockIdx.y;
  for (int k0 = 0; k0 < K; k0 += 64) {
#pragma unroll
    for (int i = 0; i < 4; ++i) {
      int seg = i * 4 + wave;
      GLD(A + (bm * 128 + seg * 8 + srow) * K + k0 + scol, As + seg * 512);
      GLD(B + (bn * 128 + seg * 8 + srow) * K + k0 + scol, Bs + seg * 512);
    }
    __syncthreads();
#pragma unroll
    for (int kk = 0; kk < 2; ++kk) {
      bf16x8 af[4], bv[4];
#pragma unroll
      for (int m = 0; m < 4; ++m)
        af[m] = *(const bf16x8*)&As[(wr * 64 + m * 16 + lr) * 64 + kk * 32 + lk * 8];
#pragma unroll
      for (int n = 0; n < 4; ++n)
        bv[n] = *(const bf16x8*)&Bs[(wc * 64 + n * 16 + lr) * 64 + kk * 32 + lk * 8];
#pragma unroll
      for (int m = 0; m < 4; ++m)
#pragma unroll
        for (int n = 0; n < 4; ++n)
          acc[m][n] = __builtin_amdgcn_mfma_f32_16x16x32_bf16(af[m], bv[n], acc[m][n], 0, 0, 0);
    }
    __syncthreads();
  }
}

// ---------------- 1x1 conv GEMM: M=256, N=8192, K=256 -> out channels 256..511 ----------------
__global__ __launch_bounds__(256) void k_gemm_out(
    const u16* __restrict__ A, const u16* __restrict__ B, float* __restrict__ out,
    const float* __restrict__ attn_b) {
  __shared__ u16 As[8192], Bs[8192];
  f32x4 acc[4][4] = {};
  gemm_core(A, B, 256, As, Bs, acc);
  const int tid = threadIdx.x;
  const int wave = tid >> 6, lane = tid & 63;
  const int wr = wave >> 1, wc = wave & 1;
  const int lr = lane & 15, lk = lane >> 4;
  const int row0 = blockIdx.x * 128 + wr * 64 + lk * 4;
  const int col0 = blockIdx.y * 128 + wc * 64 + lr;
#pragma unroll
  for (int m = 0; m < 4; ++m) {
#pragma unroll
    for (int n = 0; n < 4; ++n) {
      int col = col0 + n * 16;
      int nn = col >> 10, s = col & 1023;
#pragma unroll
      for (int j = 0; j < 4; ++j) {
        int c = row0 + m * 16 + j;
        out[((nn << 9) + 256 + c) * 1024 + s] = acc[m][n][j] + attn_b[c];
      }
    }
  }
}

extern "C" void kernel_launch(void* const* d_in, const int* in_sizes, int n_in,
                              void* d_out, int out_size, void* d_ws, size_t ws_size,
                              hipStream_t stream) {
  const float* x      = (const float*)d_in[0];
  const float* conv_w = (const float*)d_in[1];
  const float* conv_b = (const float*)d_in[2];
  const float* q_w    = (const float*)d_in[3];
  const float* q_b    = (const float*)d_in[4];
  const float* k_w    = (const float*)d_in[5];
  const float* k_b    = (const float*)d_in[6];
  const float* v_w    = (const float*)d_in[7];
  const float* v_b    = (const float*)d_in[8];
  const float* attn_w = (const float*)d_in[9];
  const float* attn_b = (const float*)d_in[10];
  const float* wm     = (const float*)d_in[11];
  const float* hm     = (const float*)d_in[12];
  float* out = (float*)d_out;
  char* ws = (char*)d_ws;

  // workspace layout (bytes), total ~42.6 MB
  u16*   W9   = (u16*)(ws + 0);         // 1024*2304*2 = 4,718,592
  u16*   W1   = (u16*)(ws + 4718592);   //  256*256*2  =   131,072
  u16*   xT   = (u16*)(ws + 4849664);   // 8192*256*2  = 4,194,304
  u16*   zpg  = (u16*)(ws + 9043968);   // 512*2       =     1,024
  u16*   qbf  = (u16*)(ws + 9044992);   // 64*1024*32*2= 4,194,304
  u16*   kbf  = (u16*)(ws + 13239296);  //               4,194,304
  u16*   vbf  = (u16*)(ws + 17433600);  //               4,194,304
  float* Bw   = (float*)(ws + 21627904);// 2M*4 =        8,388,608
  float* Bh   = (float*)(ws + 30016512);//               8,388,608
  u16*   AMT  = (u16*)(ws + 38405120);  // 8192*256*2 =  4,194,304

  hipLaunchKernelGGL(k_cast_w, dim3(1024), dim3(256), 0, stream,
                     conv_w, q_w, k_w, v_w, attn_w, W9, W1);
  hipLaunchKernelGGL(k_xT, dim3(2048), dim3(256), 0, stream, x, xT, zpg);
  hipLaunchKernelGGL(k_gemm_conv, dim3(4, 64), dim3(512), 0, stream,
                     W9, xT, zpg, out, qbf, kbf, vbf, conv_b, q_b, k_b, v_b);
  hipLaunchKernelGGL(k_bias, dim3(256), dim3(256), 0, stream, qbf, wm, hm, Bw, Bh);
  hipLaunchKernelGGL(k_attn, dim3(1024), dim3(256), 0, stream, qbf, kbf, vbf, Bw, Bh, AMT);
  hipLaunchKernelGGL(k_gemm_out, dim3(2, 64), dim3(256), 0, stream, W1, AMT, out, attn_b);
}

// Round 10
// 248.944 us; speedup vs baseline: 1.1951x; 1.0176x over previous
//
#include <hip/hip_runtime.h>
#include <hip/hip_bf16.h>

// AAConv2d: N=8, CIN=256, COUT=512, HEADS=8, DK=DV=256, MAP=32, KS=3, PAD=1
// DKH=DVH=32, CONV_OUT=256, HW=1024, K_conv = 9*256 = 2304 (order: t9=ky*3+kx major, c minor)

typedef __attribute__((ext_vector_type(8))) __bf16 bf16x8;
typedef __attribute__((ext_vector_type(4))) float f32x4;
typedef unsigned short u16;
typedef unsigned int u32;
typedef __attribute__((ext_vector_type(8))) u16 u16x8;

#define GLD(gp, lp) __builtin_amdgcn_global_load_lds( \
    (const __attribute__((address_space(1))) u32*)(gp), \
    (__attribute__((address_space(3))) u32*)(lp), 16, 0, 0)

static __device__ __forceinline__ u16 f2bf(float f) {
  u32 u = __builtin_bit_cast(u32, f);
  u += 0x7fffu + ((u >> 16) & 1u);   // round-to-nearest-even
  return (u16)(u >> 16);
}
static __device__ __forceinline__ float bf2f(u16 h) {
  return __builtin_bit_cast(float, (u32)h << 16);
}

// ---------------- cast + reorder weights to bf16 (coalesced) ----------------
__global__ __launch_bounds__(256) void k_cast_w(
    const float* __restrict__ conv_w, const float* __restrict__ q_w,
    const float* __restrict__ k_w, const float* __restrict__ v_w,
    const float* __restrict__ attn_w, u16* __restrict__ W9, u16* __restrict__ W1) {
  __shared__ float t[2304];
  int row = blockIdx.x;
  const float* src = row < 256 ? conv_w : row < 512 ? q_w : row < 768 ? k_w : v_w;
  const float* sr = src + (row & 255) * 2304;
#pragma unroll
  for (int i = threadIdx.x; i < 2304; i += 256) t[i] = sr[i];   // coalesced [c][t9]
  __syncthreads();
  u16* dr = W9 + row * 2304;
#pragma unroll
  for (int i = threadIdx.x; i < 2304; i += 256) {
    int t9 = i >> 8, c = i & 255;
    dr[i] = f2bf(t[c * 9 + t9]);
  }
  if (row < 256) W1[row * 256 + threadIdx.x] = f2bf(attn_w[row * 256 + threadIdx.x]);
}

// ---------------- x transpose: xT[n][s=y*32+x][c] bf16, + zero page ----------------
__global__ void k_xT(const float* __restrict__ x, u16* __restrict__ xT,
                     u16* __restrict__ zpage) {
  if (blockIdx.x == 0 && threadIdx.x < 512) zpage[threadIdx.x] = 0;
  __shared__ float t[32][33];
  int b = blockIdx.x;                       // 2048 blocks: n(8) x cb(8) x sb(32)
  int sb = b & 31, cb = (b >> 5) & 7, n = b >> 8;
  int s0 = sb << 5, c0 = cb << 5;
  int ls = threadIdx.x & 31, lc = threadIdx.x >> 5;  // lc 0..7
#pragma unroll
  for (int i = 0; i < 4; ++i) {
    int c = lc + i * 8;
    t[c][ls] = x[(((n << 8) + c0 + c) << 10) + s0 + ls];
  }
  __syncthreads();
#pragma unroll
  for (int i = 0; i < 4; ++i) {
    int s = lc + i * 8;
    xT[(((n << 10) + s0 + s) << 8) + c0 + ls] = f2bf(t[ls][s]);
  }
}

// ---------------- implicit conv GEMM, counted-vmcnt pipeline (R7-verified) ----------------
__global__ __launch_bounds__(512) void k_gemm_conv(
    const u16* __restrict__ A, const u16* __restrict__ xT, const u16* __restrict__ zpage,
    float* __restrict__ out,
    u16* __restrict__ qb, u16* __restrict__ kb, u16* __restrict__ vb,
    const float* __restrict__ conv_b, const float* __restrict__ q_b,
    const float* __restrict__ k_b, const float* __restrict__ v_b) {
  __shared__ u16 As[2][16384];   // 64 KB: 256 rows x 64
  __shared__ u16 Bs[2][8192];    // 32 KB: 128 rows x 64
  f32x4 acc[4][4] = {};
  const int tid = threadIdx.x;
  const int wave = tid >> 6, lane = tid & 63;
  const int wr = wave >> 1, wc = wave & 1;       // wave grid 4 (M) x 2 (N)
  const int lr = lane & 15, lk = lane >> 4;
  const int srow = lane >> 3;                    // staging row within 8-row group
  const int swz = 8 * ((lane & 7) ^ (srow & 7)); // inverse-swizzled source col (elems)
  const int bm = blockIdx.x, bn = blockIdx.y;

  int bn_y[2], bn_x[2], bn_base[2];
#pragma unroll
  for (int r = 0; r < 2; ++r) {
    int col = bn * 128 + r * 64 + wave * 8 + srow;   // ns
    int n = col >> 10, s = col & 1023;
    bn_y[r] = s >> 5;
    bn_x[r] = s & 31;
    bn_base[r] = n << 10;
  }
  const u16* a_src[4];
#pragma unroll
  for (int a = 0; a < 4; ++a)
    a_src[a] = A + (bm * 256 + a * 64 + wave * 8 + srow) * 2304 + swz;

  auto stage = [&](int buf, int t) {
    int k0 = t << 6;
    int t9 = k0 >> 8;
    int dy = t9 / 3 - 1, dx = t9 - (t9 / 3) * 3 - 1;
    int c0 = k0 & 255;
#pragma unroll
    for (int a = 0; a < 4; ++a)
      GLD(a_src[a] + k0, &As[buf][a * 4096 + wave * 512]);
#pragma unroll
    for (int r = 0; r < 2; ++r) {
      int sy = bn_y[r] + dy, sx = bn_x[r] + dx;
      bool ok = ((u32)sy < 32u) && ((u32)sx < 32u);
      const u16* src = ok ? (xT + ((bn_base[r] + (sy << 5) + sx) << 8) + c0 + swz)
                          : (zpage + swz);
      GLD(src, &Bs[buf][r * 4096 + wave * 512]);
    }
  };

  const int rswz = lr & 7;
  const int arow = (wr * 64 + lr) * 64;
  const int brow = (wc * 64 + lr) * 64;

  auto compute = [&](int buf) {
#pragma unroll
    for (int kk = 0; kk < 2; ++kk) {
      const int cswz = (((kk << 2) | lk) ^ rswz) << 3;
      bf16x8 af[4], bv[4];
#pragma unroll
      for (int m = 0; m < 4; ++m)
        af[m] = *(const bf16x8*)&As[buf][arow + m * 1024 + cswz];
#pragma unroll
      for (int n = 0; n < 4; ++n)
        bv[n] = *(const bf16x8*)&Bs[buf][brow + n * 1024 + cswz];
      __builtin_amdgcn_s_setprio(1);
#pragma unroll
      for (int m = 0; m < 4; ++m)
#pragma unroll
        for (int n = 0; n < 4; ++n)
          acc[m][n] = __builtin_amdgcn_mfma_f32_16x16x32_bf16(af[m], bv[n], acc[m][n], 0, 0, 0);
      __builtin_amdgcn_s_setprio(0);
    }
  };

  stage(0, 0);
  stage(1, 1);
  for (int t = 0; t < 35; ++t) {
    asm volatile("s_waitcnt vmcnt(6)" ::: "memory");   // tile t landed; t+1 stays in flight
    __builtin_amdgcn_s_barrier();
    compute(t & 1);
    __builtin_amdgcn_s_barrier();                      // all waves done reading buf t&1
    if (t + 2 < 36) stage(t & 1, t + 2);
  }
  asm volatile("s_waitcnt vmcnt(0)" ::: "memory");     // final tile drain
  __builtin_amdgcn_s_barrier();
  compute(35 & 1);

  const int row0 = bm * 256 + wr * 64 + lk * 4;  // C/D: row=(lane>>4)*4+j
  const int col0 = bn * 128 + wc * 64 + lr;      // C/D: col=lane&15
#pragma unroll
  for (int m = 0; m < 4; ++m) {
#pragma unroll
    for (int n = 0; n < 4; ++n) {
      int col = col0 + n * 16;
      int nn = col >> 10, s = col & 1023;
#pragma unroll
      for (int j = 0; j < 4; ++j) {
        int c = row0 + m * 16 + j;
        float v = acc[m][n][j];
        if (c < 256) {
          out[((nn << 9) + c) * 1024 + s] = v + conv_b[c];
        } else if (c < 512) {
          int cc = c - 256;
          qb[((((nn << 3) + (cc >> 5)) << 10) + s) * 32 + (cc & 31)] = f2bf(v + q_b[cc]);
        } else if (c < 768) {
          int cc = c - 512;
          kb[((((nn << 3) + (cc >> 5)) << 10) + s) * 32 + (cc & 31)] = f2bf(v + k_b[cc]);
        } else {
          int cc = c - 768;
          vb[((nn << 8) + cc) * 1024 + s] = f2bf(v + v_b[cc]);
        }
      }
    }
  }
}

// ---------------- rel-position bias tables (LDS-staged wm/hm) ----------------
__global__ __launch_bounds__(256) void k_bias(const u16* __restrict__ qb,
                                              const float* __restrict__ wm,
                                              const float* __restrict__ hm,
                                              float* __restrict__ Bw, float* __restrict__ Bh) {
  __shared__ float wl[63 * 36], hl[63 * 36];   // stride 36: 16B-aligned rows, bank-spread
  for (int i = threadIdx.x; i < 2016; i += 256) {
    int r = i >> 5, c = i & 31;
    wl[r * 36 + c] = wm[i];
    hl[r * 36 + c] = hm[i];
  }
  __syncthreads();
  int pos = blockIdx.x * blockDim.x + threadIdx.x;  // 65536
  int s = pos & 1023;
  int y = s >> 5, xx = s & 31;
  float q[32];
  const u16x8* q8 = (const u16x8*)(qb + pos * 32);
#pragma unroll
  for (int v = 0; v < 4; ++v) {
    u16x8 w = q8[v];
#pragma unroll
    for (int e = 0; e < 8; ++e) q[v * 8 + e] = bf2f(w[e]);
  }
  float* bwo = Bw + pos * 32;
  float* bho = Bh + pos * 32;
#pragma unroll 4
  for (int r = 0; r < 32; ++r) {
    const f32x4* wr = (const f32x4*)&wl[(r - xx + 31) * 36];
    const f32x4* hr = (const f32x4*)&hl[(r - y + 31) * 36];
    float aw = 0.f, ah = 0.f;
#pragma unroll
    for (int i = 0; i < 8; ++i) {
      f32x4 wv = wr[i], hv = hr[i];
#pragma unroll
      for (int e = 0; e < 4; ++e) {
        float qd = q[i * 4 + e];
        aw += qd * wv[e];
        ah += qd * hv[e];
      }
    }
    bwo[r] = aw;
    bho[r] = ah;
  }
}

// ---------------- flash attention, deferred-PV pipeline ----------------
// Iter kt: QK^T + softmax for tile kt (write P_kt to per-wave dbuf), PV MFMA for tile kt-1.
// The lgkmcnt(0) before the P-read waits on writes issued a full iteration ago (free).
// Algebra: o enters iter kt = sum_{t<=kt-2} P_t V_t @ scale m_{kt-2}; apply o = o*sf_{kt-1}
// + P_{kt-1} V_{kt-1}; epilogue finishes tile 15. Identical arithmetic, reordered.
__global__ __launch_bounds__(256) void k_attn(
    const u16* __restrict__ qb, const u16* __restrict__ kb, const u16* __restrict__ vb,
    const float* __restrict__ Bw, const float* __restrict__ Bh, u16* __restrict__ AMT) {
  __shared__ u16 Pl[4][2][16 * 72];  // per-wave double-buffered P tile 16x64, stride 72
  const int wave = threadIdx.x >> 6, lane = threadIdx.x & 63;
  const int task = blockIdx.x * 4 + wave;  // 4096 tasks = 64 nh * 64 q-groups
  const int nh = task >> 6, qg = task & 63;
  const int n = nh >> 3, h = nh & 7;
  const int qbase = qg << 4;
  const int lr = lane & 15, lg = lane >> 4;

  bf16x8 aq = *(const bf16x8*)&qb[((nh << 10) + qbase + lr) * 32 + lg * 8];

  float Bwr[2][4];
#pragma unroll
  for (int p = 0; p < 2; ++p)
#pragma unroll
    for (int j = 0; j < 4; ++j)
      Bwr[p][j] = Bw[((nh << 10) + qbase + lg * 4 + j) * 32 + p * 16 + lr];

  float mrow[4] = {-1e30f, -1e30f, -1e30f, -1e30f};
  float lrow[4] = {0.f, 0.f, 0.f, 0.f};
  float sfp[4] = {1.f, 1.f, 1.f, 1.f};   // rescale factor from previous iter
  f32x4 o[2] = {};
  u16* plw = &Pl[wave][0][0];
  const int vrow0 = ((n << 8) + (h << 5) + lr) * 1024;        // dn=0 V row base
  const int vrow1 = ((n << 8) + (h << 5) + 16 + lr) * 1024;   // dn=1

  for (int kt = 0; kt < 16; ++kt) {
    const int cur = (kt & 1) * 1152, prv = ((kt & 1) ^ 1) * 1152;
    // ---- QK^T for tile kt ----
    f32x4 zero = {0.f, 0.f, 0.f, 0.f};
    f32x4 sf_[4];
#pragma unroll
    for (int f = 0; f < 4; ++f) {
      bf16x8 bk = *(const bf16x8*)&kb[((nh << 10) + (kt << 6) + f * 16 + lr) * 32 + lg * 8];
      sf_[f] = __builtin_amdgcn_mfma_f32_16x16x32_bf16(aq, bk, zero, 0, 0, 0);
    }
    float Bhr[2][4];  // ky = kt*2 + p, contiguous pair -> float2
#pragma unroll
    for (int j = 0; j < 4; ++j) {
      float2 bh2 = *(const float2*)&Bh[((nh << 10) + qbase + lg * 4 + j) * 32 + (kt << 1)];
      Bhr[0][j] = bh2.x;
      Bhr[1][j] = bh2.y;
    }
    float tv[4][4];
#pragma unroll
    for (int f = 0; f < 4; ++f)   // k col = f*16+lr -> kx=(f&1)*16+lr, ky_local=f>>1
#pragma unroll
      for (int j = 0; j < 4; ++j)
        tv[f][j] = (sf_[f][j] + Bhr[f >> 1][j] + Bwr[f & 1][j]) * 0.17677669529663687f;

    // ---- softmax for tile kt ----
    float pv[4][4], sf[4];
#pragma unroll
    for (int j = 0; j < 4; ++j) {
      float vmax = fmaxf(fmaxf(tv[0][j], tv[1][j]), fmaxf(tv[2][j], tv[3][j]));
#pragma unroll
      for (int d = 1; d < 16; d <<= 1) vmax = fmaxf(vmax, __shfl_xor(vmax, d, 64));
      float mn = fmaxf(mrow[j], vmax);
      sf[j] = __expf(mrow[j] - mn);
      mrow[j] = mn;
      float sum = 0.f;
#pragma unroll
      for (int f = 0; f < 4; ++f) {
        float e = __expf(tv[f][j] - mn);
        pv[f][j] = e;
        sum += e;
      }
#pragma unroll
      for (int d = 1; d < 16; d <<= 1) sum += __shfl_xor(sum, d, 64);
      lrow[j] = lrow[j] * sf[j] + sum;
    }

    // ---- PV for tile kt-1 (P writes from last iter: lgkmcnt wait is free) ----
    if (kt > 0) {
      asm volatile("s_waitcnt lgkmcnt(0)" ::: "memory");
      __builtin_amdgcn_sched_barrier(0);   // rule #18
      bf16x8 pa0 = *(const bf16x8*)&plw[prv + lr * 72 + lg * 8];
      bf16x8 pa1 = *(const bf16x8*)&plw[prv + lr * 72 + 32 + lg * 8];
#pragma unroll
      for (int dn = 0; dn < 2; ++dn)
#pragma unroll
        for (int j = 0; j < 4; ++j) o[dn][j] *= sfp[j];
      const int kv = (kt - 1) << 6;
      bf16x8 bv00 = *(const bf16x8*)&vb[vrow0 + kv + lg * 8];
      bf16x8 bv01 = *(const bf16x8*)&vb[vrow0 + kv + 32 + lg * 8];
      bf16x8 bv10 = *(const bf16x8*)&vb[vrow1 + kv + lg * 8];
      bf16x8 bv11 = *(const bf16x8*)&vb[vrow1 + kv + 32 + lg * 8];
      o[0] = __builtin_amdgcn_mfma_f32_16x16x32_bf16(pa0, bv00, o[0], 0, 0, 0);
      o[0] = __builtin_amdgcn_mfma_f32_16x16x32_bf16(pa1, bv01, o[0], 0, 0, 0);
      o[1] = __builtin_amdgcn_mfma_f32_16x16x32_bf16(pa0, bv10, o[1], 0, 0, 0);
      o[1] = __builtin_amdgcn_mfma_f32_16x16x32_bf16(pa1, bv11, o[1], 0, 0, 0);
    }

    // ---- write P_kt into current buffer (read next iter) ----
#pragma unroll
    for (int f = 0; f < 4; ++f)
#pragma unroll
      for (int j = 0; j < 4; ++j)
        plw[cur + (lg * 4 + j) * 72 + f * 16 + lr] = f2bf(pv[f][j]);
#pragma unroll
    for (int j = 0; j < 4; ++j) sfp[j] = sf[j];
  }

  // ---- epilogue: PV for tile 15 ----
  {
    asm volatile("s_waitcnt lgkmcnt(0)" ::: "memory");
    __builtin_amdgcn_sched_barrier(0);
    const int prv = 1152;  // kt=15 wrote buffer 1
    bf16x8 pa0 = *(const bf16x8*)&plw[prv + lr * 72 + lg * 8];
    bf16x8 pa1 = *(const bf16x8*)&plw[prv + lr * 72 + 32 + lg * 8];
#pragma unroll
    for (int dn = 0; dn < 2; ++dn)
#pragma unroll
      for (int j = 0; j < 4; ++j) o[dn][j] *= sfp[j];
    const int kv = 15 << 6;
    bf16x8 bv00 = *(const bf16x8*)&vb[vrow0 + kv + lg * 8];
    bf16x8 bv01 = *(const bf16x8*)&vb[vrow0 + kv + 32 + lg * 8];
    bf16x8 bv10 = *(const bf16x8*)&vb[vrow1 + kv + lg * 8];
    bf16x8 bv11 = *(const bf16x8*)&vb[vrow1 + kv + 32 + lg * 8];
    o[0] = __builtin_amdgcn_mfma_f32_16x16x32_bf16(pa0, bv00, o[0], 0, 0, 0);
    o[0] = __builtin_amdgcn_mfma_f32_16x16x32_bf16(pa1, bv01, o[0], 0, 0, 0);
    o[1] = __builtin_amdgcn_mfma_f32_16x16x32_bf16(pa0, bv10, o[1], 0, 0, 0);
    o[1] = __builtin_amdgcn_mfma_f32_16x16x32_bf16(pa1, bv11, o[1], 0, 0, 0);
  }

#pragma unroll
  for (int dn = 0; dn < 2; ++dn)
#pragma unroll
    for (int j = 0; j < 4; ++j) {
      int q = qbase + lg * 4 + j;
      int d = dn * 16 + lr;
      float v = o[dn][j] / lrow[j];
      AMT[((n << 10) + ((q & 31) << 5) + d) * 256 + (h << 5) + (q >> 5)] = f2bf(v);
    }
}

// ---------------- 1x1 conv GEMM: M=256, N=8192, K=256 -> out channels 256..511 ----------------
// 128x64 tile, grid (2,128) = 256 blocks (full GPU). 4 waves: 2M x 2N of 64x32.
__global__ __launch_bounds__(256) void k_gemm_out(
    const u16* __restrict__ A, const u16* __restrict__ B, float* __restrict__ out,
    const float* __restrict__ attn_b) {
  __shared__ u16 As[16384], Bs[8192];
  f32x4 acc[4][2] = {};
  const int tid = threadIdx.x;
  const int wave = tid >> 6, lane = tid & 63;
  const int wr = wave >> 1, wc = wave & 1;
  const int lr = lane & 15, lk = lane >> 4;
  const int srow = lane >> 3;
  const int scol = (lane & 7) << 3;
  const int bm = blockIdx.x, bn = blockIdx.y;
  for (int k0 = 0; k0 < 256; k0 += 64) {
#pragma unroll
    for (int i = 0; i < 4; ++i) {
      int seg = i * 4 + wave;        // A: 16 segs of 8 rows
      GLD(A + (bm * 128 + seg * 8 + srow) * 256 + k0 + scol, As + seg * 512);
    }
#pragma unroll
    for (int i = 0; i < 2; ++i) {
      int seg = i * 4 + wave;        // B: 8 segs of 8 rows
      GLD(B + (bn * 64 + seg * 8 + srow) * 256 + k0 + scol, Bs + seg * 512);
    }
    __syncthreads();
#pragma unroll
    for (int kk = 0; kk < 2; ++kk) {
      bf16x8 af[4], bv[2];
#pragma unroll
      for (int m = 0; m < 4; ++m)
        af[m] = *(const bf16x8*)&As[(wr * 64 + m * 16 + lr) * 64 + kk * 32 + lk * 8];
#pragma unroll
      for (int n = 0; n < 2; ++n)
        bv[n] = *(const bf16x8*)&Bs[(wc * 32 + n * 16 + lr) * 64 + kk * 32 + lk * 8];
#pragma unroll
      for (int m = 0; m < 4; ++m)
#pragma unroll
        for (int n = 0; n < 2; ++n)
          acc[m][n] = __builtin_amdgcn_mfma_f32_16x16x32_bf16(af[m], bv[n], acc[m][n], 0, 0, 0);
    }
    __syncthreads();
  }
  const int row0 = bm * 128 + wr * 64 + lk * 4;
  const int col0 = bn * 64 + wc * 32 + lr;
#pragma unroll
  for (int m = 0; m < 4; ++m) {
#pragma unroll
    for (int n = 0; n < 2; ++n) {
      int col = col0 + n * 16;
      int nn = col >> 10, s = col & 1023;
#pragma unroll
      for (int j = 0; j < 4; ++j) {
        int c = row0 + m * 16 + j;
        out[((nn << 9) + 256 + c) * 1024 + s] = acc[m][n][j] + attn_b[c];
      }
    }
  }
}

extern "C" void kernel_launch(void* const* d_in, const int* in_sizes, int n_in,
                              void* d_out, int out_size, void* d_ws, size_t ws_size,
                              hipStream_t stream) {
  const float* x      = (const float*)d_in[0];
  const float* conv_w = (const float*)d_in[1];
  const float* conv_b = (const float*)d_in[2];
  const float* q_w    = (const float*)d_in[3];
  const float* q_b    = (const float*)d_in[4];
  const float* k_w    = (const float*)d_in[5];
  const float* k_b    = (const float*)d_in[6];
  const float* v_w    = (const float*)d_in[7];
  const float* v_b    = (const float*)d_in[8];
  const float* attn_w = (const float*)d_in[9];
  const float* attn_b = (const float*)d_in[10];
  const float* wm     = (const float*)d_in[11];
  const float* hm     = (const float*)d_in[12];
  float* out = (float*)d_out;
  char* ws = (char*)d_ws;

  // workspace layout (bytes), total ~42.6 MB
  u16*   W9   = (u16*)(ws + 0);         // 1024*2304*2 = 4,718,592
  u16*   W1   = (u16*)(ws + 4718592);   //  256*256*2  =   131,072
  u16*   xT   = (u16*)(ws + 4849664);   // 8192*256*2  = 4,194,304
  u16*   zpg  = (u16*)(ws + 9043968);   // 512*2       =     1,024
  u16*   qbf  = (u16*)(ws + 9044992);   // 64*1024*32*2= 4,194,304
  u16*   kbf  = (u16*)(ws + 13239296);  //               4,194,304
  u16*   vbf  = (u16*)(ws + 17433600);  //               4,194,304
  float* Bw   = (float*)(ws + 21627904);// 2M*4 =        8,388,608
  float* Bh   = (float*)(ws + 30016512);//               8,388,608
  u16*   AMT  = (u16*)(ws + 38405120);  // 8192*256*2 =  4,194,304

  hipLaunchKernelGGL(k_cast_w, dim3(1024), dim3(256), 0, stream,
                     conv_w, q_w, k_w, v_w, attn_w, W9, W1);
  hipLaunchKernelGGL(k_xT, dim3(2048), dim3(256), 0, stream, x, xT, zpg);
  hipLaunchKernelGGL(k_gemm_conv, dim3(4, 64), dim3(512), 0, stream,
                     W9, xT, zpg, out, qbf, kbf, vbf, conv_b, q_b, k_b, v_b);
  hipLaunchKernelGGL(k_bias, dim3(256), dim3(256), 0, stream, qbf, wm, hm, Bw, Bh);
  hipLaunchKernelGGL(k_attn, dim3(1024), dim3(256), 0, stream, qbf, kbf, vbf, Bw, Bh, AMT);
  hipLaunchKernelGGL(k_gemm_out, dim3(2, 128), dim3(256), 0, stream, W1, AMT, out, attn_b);
}

// Round 11
// 237.181 us; speedup vs baseline: 1.2544x; 1.0496x over previous
//
#include <hip/hip_runtime.h>
#include <hip/hip_bf16.h>

// AAConv2d: N=8, CIN=256, COUT=512, HEADS=8, DK=DV=256, MAP=32, KS=3, PAD=1
// DKH=DVH=32, CONV_OUT=256, HW=1024, K_conv = 9*256 = 2304 (order: t9=ky*3+kx major, c minor)

typedef __attribute__((ext_vector_type(8))) __bf16 bf16x8;
typedef __attribute__((ext_vector_type(4))) float f32x4;
typedef unsigned short u16;
typedef unsigned int u32;
typedef __attribute__((ext_vector_type(8))) u16 u16x8;

#define GLD(gp, lp) __builtin_amdgcn_global_load_lds( \
    (const __attribute__((address_space(1))) u32*)(gp), \
    (__attribute__((address_space(3))) u32*)(lp), 16, 0, 0)

static __device__ __forceinline__ u16 f2bf(float f) {
  u32 u = __builtin_bit_cast(u32, f);
  u += 0x7fffu + ((u >> 16) & 1u);   // round-to-nearest-even
  return (u16)(u >> 16);
}
static __device__ __forceinline__ float bf2f(u16 h) {
  return __builtin_bit_cast(float, (u32)h << 16);
}

// ---------------- cast + reorder weights to bf16 (coalesced) ----------------
__global__ __launch_bounds__(256) void k_cast_w(
    const float* __restrict__ conv_w, const float* __restrict__ q_w,
    const float* __restrict__ k_w, const float* __restrict__ v_w,
    const float* __restrict__ attn_w, u16* __restrict__ W9, u16* __restrict__ W1) {
  __shared__ float t[2304];
  int row = blockIdx.x;
  const float* src = row < 256 ? conv_w : row < 512 ? q_w : row < 768 ? k_w : v_w;
  const float* sr = src + (row & 255) * 2304;
#pragma unroll
  for (int i = threadIdx.x; i < 2304; i += 256) t[i] = sr[i];   // coalesced [c][t9]
  __syncthreads();
  u16* dr = W9 + row * 2304;
#pragma unroll
  for (int i = threadIdx.x; i < 2304; i += 256) {
    int t9 = i >> 8, c = i & 255;
    dr[i] = f2bf(t[c * 9 + t9]);
  }
  if (row < 256) W1[row * 256 + threadIdx.x] = f2bf(attn_w[row * 256 + threadIdx.x]);
}

// ---------------- x transpose: xT[n][s=y*32+x][c] bf16, + zero page ----------------
__global__ void k_xT(const float* __restrict__ x, u16* __restrict__ xT,
                     u16* __restrict__ zpage) {
  if (blockIdx.x == 0 && threadIdx.x < 512) zpage[threadIdx.x] = 0;
  __shared__ float t[32][33];
  int b = blockIdx.x;                       // 2048 blocks: n(8) x cb(8) x sb(32)
  int sb = b & 31, cb = (b >> 5) & 7, n = b >> 8;
  int s0 = sb << 5, c0 = cb << 5;
  int ls = threadIdx.x & 31, lc = threadIdx.x >> 5;  // lc 0..7
#pragma unroll
  for (int i = 0; i < 4; ++i) {
    int c = lc + i * 8;
    t[c][ls] = x[(((n << 8) + c0 + c) << 10) + s0 + ls];
  }
  __syncthreads();
#pragma unroll
  for (int i = 0; i < 4; ++i) {
    int s = lc + i * 8;
    xT[(((n << 10) + s0 + s) << 8) + c0 + ls] = f2bf(t[ls][s]);
  }
}

// ---------------- implicit conv GEMM, counted-vmcnt pipeline, 128x128 @ 2 blocks/CU ----------------
// M=1024 x N=8192 x K=2304. BM=128, BN=128, BK=64, 8 waves (2M x 4N of 64x32 out).
// grid (8,64)=512 blocks = 2/CU; LDS 64KB -> both blocks resident (cross-block stall cover).
// T2 both-sides swizzle (R7-verified); T4 counted vmcnt(4); T5 setprio.
__global__ __launch_bounds__(512) void k_gemm_conv(
    const u16* __restrict__ A, const u16* __restrict__ xT, const u16* __restrict__ zpage,
    float* __restrict__ out,
    u16* __restrict__ qb, u16* __restrict__ kb, u16* __restrict__ vb,
    const float* __restrict__ conv_b, const float* __restrict__ q_b,
    const float* __restrict__ k_b, const float* __restrict__ v_b) {
  __shared__ u16 As[2][8192];    // 32 KB: 128 rows x 64
  __shared__ u16 Bs[2][8192];    // 32 KB: 128 rows x 64
  f32x4 acc[4][2] = {};
  const int tid = threadIdx.x;
  const int wave = tid >> 6, lane = tid & 63;
  const int wr = wave >> 2, wc = wave & 3;       // wave grid 2 (M) x 4 (N)
  const int lr = lane & 15, lk = lane >> 4;
  const int srow = lane >> 3;                    // staging row within 8-row group
  const int swz = 8 * ((lane & 7) ^ (srow & 7)); // inverse-swizzled source col (elems)
  const int bm = blockIdx.x, bn = blockIdx.y;

  // B-row geometry (constant over K): 2 issues/wave, rows (r*8+wave)*8 + srow
  int bn_y[2], bn_x[2], bn_base[2];
#pragma unroll
  for (int r = 0; r < 2; ++r) {
    int col = bn * 128 + (r * 8 + wave) * 8 + srow;   // ns
    int n = col >> 10, s = col & 1023;
    bn_y[r] = s >> 5;
    bn_x[r] = s & 31;
    bn_base[r] = n << 10;
  }
  // A source rows: 2 issues/wave
  const u16* a_src[2];
#pragma unroll
  for (int a = 0; a < 2; ++a)
    a_src[a] = A + (bm * 128 + (a * 8 + wave) * 8 + srow) * 2304 + swz;

  auto stage = [&](int buf, int t) {
    int k0 = t << 6;
    int t9 = k0 >> 8;
    int dy = t9 / 3 - 1, dx = t9 - (t9 / 3) * 3 - 1;
    int c0 = k0 & 255;
#pragma unroll
    for (int a = 0; a < 2; ++a)
      GLD(a_src[a] + k0, &As[buf][(a * 8 + wave) * 512]);
#pragma unroll
    for (int r = 0; r < 2; ++r) {
      int sy = bn_y[r] + dy, sx = bn_x[r] + dx;
      bool ok = ((u32)sy < 32u) && ((u32)sx < 32u);
      const u16* src = ok ? (xT + ((bn_base[r] + (sy << 5) + sx) << 8) + c0 + swz)
                          : (zpage + swz);
      GLD(src, &Bs[buf][(r * 8 + wave) * 512]);
    }
  };

  const int rswz = lr & 7;
  const int arow = (wr * 64 + lr) * 64;   // + m*16*64
  const int brow = (wc * 32 + lr) * 64;   // + n*16*64

  auto compute = [&](int buf) {
#pragma unroll
    for (int kk = 0; kk < 2; ++kk) {
      const int cswz = (((kk << 2) | lk) ^ rswz) << 3;
      bf16x8 af[4], bv[2];
#pragma unroll
      for (int m = 0; m < 4; ++m)
        af[m] = *(const bf16x8*)&As[buf][arow + m * 1024 + cswz];
#pragma unroll
      for (int n = 0; n < 2; ++n)
        bv[n] = *(const bf16x8*)&Bs[buf][brow + n * 1024 + cswz];
      __builtin_amdgcn_s_setprio(1);
#pragma unroll
      for (int m = 0; m < 4; ++m)
#pragma unroll
        for (int n = 0; n < 2; ++n)
          acc[m][n] = __builtin_amdgcn_mfma_f32_16x16x32_bf16(af[m], bv[n], acc[m][n], 0, 0, 0);
      __builtin_amdgcn_s_setprio(0);
    }
  };

  stage(0, 0);
  stage(1, 1);
  for (int t = 0; t < 35; ++t) {
    asm volatile("s_waitcnt vmcnt(4)" ::: "memory");   // tile t landed; t+1 stays in flight
    __builtin_amdgcn_s_barrier();
    compute(t & 1);
    __builtin_amdgcn_s_barrier();                      // all waves done reading buf t&1
    if (t + 2 < 36) stage(t & 1, t + 2);
  }
  asm volatile("s_waitcnt vmcnt(0)" ::: "memory");     // final tile drain
  __builtin_amdgcn_s_barrier();
  compute(35 & 1);

  const int row0 = bm * 128 + wr * 64 + lk * 4;  // C/D: row=(lane>>4)*4+j
  const int col0 = bn * 128 + wc * 32 + lr;      // C/D: col=lane&15
#pragma unroll
  for (int m = 0; m < 4; ++m) {
#pragma unroll
    for (int n = 0; n < 2; ++n) {
      int col = col0 + n * 16;
      int nn = col >> 10, s = col & 1023;
#pragma unroll
      for (int j = 0; j < 4; ++j) {
        int c = row0 + m * 16 + j;
        float v = acc[m][n][j];
        if (c < 256) {
          out[((nn << 9) + c) * 1024 + s] = v + conv_b[c];
        } else if (c < 512) {
          int cc = c - 256;
          qb[((((nn << 3) + (cc >> 5)) << 10) + s) * 32 + (cc & 31)] = f2bf(v + q_b[cc]);
        } else if (c < 768) {
          int cc = c - 512;
          kb[((((nn << 3) + (cc >> 5)) << 10) + s) * 32 + (cc & 31)] = f2bf(v + k_b[cc]);
        } else {
          int cc = c - 768;
          vb[((nn << 8) + cc) * 1024 + s] = f2bf(v + v_b[cc]);
        }
      }
    }
  }
}

// ---------------- rel-position bias tables (LDS-staged wm/hm) ----------------
__global__ __launch_bounds__(256) void k_bias(const u16* __restrict__ qb,
                                              const float* __restrict__ wm,
                                              const float* __restrict__ hm,
                                              float* __restrict__ Bw, float* __restrict__ Bh) {
  __shared__ float wl[63 * 36], hl[63 * 36];   // stride 36: 16B-aligned rows, bank-spread
  for (int i = threadIdx.x; i < 2016; i += 256) {
    int r = i >> 5, c = i & 31;
    wl[r * 36 + c] = wm[i];
    hl[r * 36 + c] = hm[i];
  }
  __syncthreads();
  int pos = blockIdx.x * blockDim.x + threadIdx.x;  // 65536
  int s = pos & 1023;
  int y = s >> 5, xx = s & 31;
  float q[32];
  const u16x8* q8 = (const u16x8*)(qb + pos * 32);
#pragma unroll
  for (int v = 0; v < 4; ++v) {
    u16x8 w = q8[v];
#pragma unroll
    for (int e = 0; e < 8; ++e) q[v * 8 + e] = bf2f(w[e]);
  }
  float* bwo = Bw + pos * 32;
  float* bho = Bh + pos * 32;
#pragma unroll 4
  for (int r = 0; r < 32; ++r) {
    const f32x4* wr = (const f32x4*)&wl[(r - xx + 31) * 36];
    const f32x4* hr = (const f32x4*)&hl[(r - y + 31) * 36];
    float aw = 0.f, ah = 0.f;
#pragma unroll
    for (int i = 0; i < 8; ++i) {
      f32x4 wv = wr[i], hv = hr[i];
#pragma unroll
      for (int e = 0; e < 4; ++e) {
        float qd = q[i * 4 + e];
        aw += qd * wv[e];
        ah += qd * hv[e];
      }
    }
    bwo[r] = aw;
    bho[r] = ah;
  }
}

// ---------------- flash attention, deferred-PV pipeline (R10-verified) ----------------
__global__ __launch_bounds__(256) void k_attn(
    const u16* __restrict__ qb, const u16* __restrict__ kb, const u16* __restrict__ vb,
    const float* __restrict__ Bw, const float* __restrict__ Bh, u16* __restrict__ AMT) {
  __shared__ u16 Pl[4][2][16 * 72];  // per-wave double-buffered P tile 16x64, stride 72
  const int wave = threadIdx.x >> 6, lane = threadIdx.x & 63;
  const int task = blockIdx.x * 4 + wave;  // 4096 tasks = 64 nh * 64 q-groups
  const int nh = task >> 6, qg = task & 63;
  const int n = nh >> 3, h = nh & 7;
  const int qbase = qg << 4;
  const int lr = lane & 15, lg = lane >> 4;

  bf16x8 aq = *(const bf16x8*)&qb[((nh << 10) + qbase + lr) * 32 + lg * 8];

  float Bwr[2][4];
#pragma unroll
  for (int p = 0; p < 2; ++p)
#pragma unroll
    for (int j = 0; j < 4; ++j)
      Bwr[p][j] = Bw[((nh << 10) + qbase + lg * 4 + j) * 32 + p * 16 + lr];

  float mrow[4] = {-1e30f, -1e30f, -1e30f, -1e30f};
  float lrow[4] = {0.f, 0.f, 0.f, 0.f};
  float sfp[4] = {1.f, 1.f, 1.f, 1.f};   // rescale factor from previous iter
  f32x4 o[2] = {};
  u16* plw = &Pl[wave][0][0];
  const int vrow0 = ((n << 8) + (h << 5) + lr) * 1024;        // dn=0 V row base
  const int vrow1 = ((n << 8) + (h << 5) + 16 + lr) * 1024;   // dn=1

  for (int kt = 0; kt < 16; ++kt) {
    const int cur = (kt & 1) * 1152, prv = ((kt & 1) ^ 1) * 1152;
    // ---- QK^T for tile kt ----
    f32x4 zero = {0.f, 0.f, 0.f, 0.f};
    f32x4 sf_[4];
#pragma unroll
    for (int f = 0; f < 4; ++f) {
      bf16x8 bk = *(const bf16x8*)&kb[((nh << 10) + (kt << 6) + f * 16 + lr) * 32 + lg * 8];
      sf_[f] = __builtin_amdgcn_mfma_f32_16x16x32_bf16(aq, bk, zero, 0, 0, 0);
    }
    float Bhr[2][4];  // ky = kt*2 + p, contiguous pair -> float2
#pragma unroll
    for (int j = 0; j < 4; ++j) {
      float2 bh2 = *(const float2*)&Bh[((nh << 10) + qbase + lg * 4 + j) * 32 + (kt << 1)];
      Bhr[0][j] = bh2.x;
      Bhr[1][j] = bh2.y;
    }
    float tv[4][4];
#pragma unroll
    for (int f = 0; f < 4; ++f)   // k col = f*16+lr -> kx=(f&1)*16+lr, ky_local=f>>1
#pragma unroll
      for (int j = 0; j < 4; ++j)
        tv[f][j] = (sf_[f][j] + Bhr[f >> 1][j] + Bwr[f & 1][j]) * 0.17677669529663687f;

    // ---- softmax for tile kt ----
    float pv[4][4], sf[4];
#pragma unroll
    for (int j = 0; j < 4; ++j) {
      float vmax = fmaxf(fmaxf(tv[0][j], tv[1][j]), fmaxf(tv[2][j], tv[3][j]));
#pragma unroll
      for (int d = 1; d < 16; d <<= 1) vmax = fmaxf(vmax, __shfl_xor(vmax, d, 64));
      float mn = fmaxf(mrow[j], vmax);
      sf[j] = __expf(mrow[j] - mn);
      mrow[j] = mn;
      float sum = 0.f;
#pragma unroll
      for (int f = 0; f < 4; ++f) {
        float e = __expf(tv[f][j] - mn);
        pv[f][j] = e;
        sum += e;
      }
#pragma unroll
      for (int d = 1; d < 16; d <<= 1) sum += __shfl_xor(sum, d, 64);
      lrow[j] = lrow[j] * sf[j] + sum;
    }

    // ---- PV for tile kt-1 (P writes from last iter: lgkmcnt wait is free) ----
    if (kt > 0) {
      asm volatile("s_waitcnt lgkmcnt(0)" ::: "memory");
      __builtin_amdgcn_sched_barrier(0);   // rule #18
      bf16x8 pa0 = *(const bf16x8*)&plw[prv + lr * 72 + lg * 8];
      bf16x8 pa1 = *(const bf16x8*)&plw[prv + lr * 72 + 32 + lg * 8];
#pragma unroll
      for (int dn = 0; dn < 2; ++dn)
#pragma unroll
        for (int j = 0; j < 4; ++j) o[dn][j] *= sfp[j];
      const int kv = (kt - 1) << 6;
      bf16x8 bv00 = *(const bf16x8*)&vb[vrow0 + kv + lg * 8];
      bf16x8 bv01 = *(const bf16x8*)&vb[vrow0 + kv + 32 + lg * 8];
      bf16x8 bv10 = *(const bf16x8*)&vb[vrow1 + kv + lg * 8];
      bf16x8 bv11 = *(const bf16x8*)&vb[vrow1 + kv + 32 + lg * 8];
      o[0] = __builtin_amdgcn_mfma_f32_16x16x32_bf16(pa0, bv00, o[0], 0, 0, 0);
      o[0] = __builtin_amdgcn_mfma_f32_16x16x32_bf16(pa1, bv01, o[0], 0, 0, 0);
      o[1] = __builtin_amdgcn_mfma_f32_16x16x32_bf16(pa0, bv10, o[1], 0, 0, 0);
      o[1] = __builtin_amdgcn_mfma_f32_16x16x32_bf16(pa1, bv11, o[1], 0, 0, 0);
    }

    // ---- write P_kt into current buffer (read next iter) ----
#pragma unroll
    for (int f = 0; f < 4; ++f)
#pragma unroll
      for (int j = 0; j < 4; ++j)
        plw[cur + (lg * 4 + j) * 72 + f * 16 + lr] = f2bf(pv[f][j]);
#pragma unroll
    for (int j = 0; j < 4; ++j) sfp[j] = sf[j];
  }

  // ---- epilogue: PV for tile 15 ----
  {
    asm volatile("s_waitcnt lgkmcnt(0)" ::: "memory");
    __builtin_amdgcn_sched_barrier(0);
    const int prv = 1152;  // kt=15 wrote buffer 1
    bf16x8 pa0 = *(const bf16x8*)&plw[prv + lr * 72 + lg * 8];
    bf16x8 pa1 = *(const bf16x8*)&plw[prv + lr * 72 + 32 + lg * 8];
#pragma unroll
    for (int dn = 0; dn < 2; ++dn)
#pragma unroll
      for (int j = 0; j < 4; ++j) o[dn][j] *= sfp[j];
    const int kv = 15 << 6;
    bf16x8 bv00 = *(const bf16x8*)&vb[vrow0 + kv + lg * 8];
    bf16x8 bv01 = *(const bf16x8*)&vb[vrow0 + kv + 32 + lg * 8];
    bf16x8 bv10 = *(const bf16x8*)&vb[vrow1 + kv + lg * 8];
    bf16x8 bv11 = *(const bf16x8*)&vb[vrow1 + kv + 32 + lg * 8];
    o[0] = __builtin_amdgcn_mfma_f32_16x16x32_bf16(pa0, bv00, o[0], 0, 0, 0);
    o[0] = __builtin_amdgcn_mfma_f32_16x16x32_bf16(pa1, bv01, o[0], 0, 0, 0);
    o[1] = __builtin_amdgcn_mfma_f32_16x16x32_bf16(pa0, bv10, o[1], 0, 0, 0);
    o[1] = __builtin_amdgcn_mfma_f32_16x16x32_bf16(pa1, bv11, o[1], 0, 0, 0);
  }

#pragma unroll
  for (int dn = 0; dn < 2; ++dn)
#pragma unroll
    for (int j = 0; j < 4; ++j) {
      int q = qbase + lg * 4 + j;
      int d = dn * 16 + lr;
      float v = o[dn][j] / lrow[j];
      AMT[((n << 10) + ((q & 31) << 5) + d) * 256 + (h << 5) + (q >> 5)] = f2bf(v);
    }
}

// ---------------- 1x1 conv GEMM: M=256, N=8192, K=256 -> out channels 256..511 ----------------
// 64x64 tile, grid (4,128) = 512 blocks = 2/CU. 4 waves: 2M x 2N of 32x32 each.
__global__ __launch_bounds__(256) void k_gemm_out(
    const u16* __restrict__ A, const u16* __restrict__ B, float* __restrict__ out,
    const float* __restrict__ attn_b) {
  __shared__ u16 As[4096], Bs[4096];
  f32x4 acc[2][2] = {};
  const int tid = threadIdx.x;
  const int wave = tid >> 6, lane = tid & 63;
  const int wr = wave >> 1, wc = wave & 1;
  const int lr = lane & 15, lk = lane >> 4;
  const int srow = lane >> 3;
  const int scol = (lane & 7) << 3;
  const int bm = blockIdx.x, bn = blockIdx.y;
  for (int k0 = 0; k0 < 256; k0 += 64) {
#pragma unroll
    for (int i = 0; i < 2; ++i) {
      int seg = i * 4 + wave;        // 8 segs of 8 rows each
      GLD(A + (bm * 64 + seg * 8 + srow) * 256 + k0 + scol, As + seg * 512);
      GLD(B + (bn * 64 + seg * 8 + srow) * 256 + k0 + scol, Bs + seg * 512);
    }
    __syncthreads();
#pragma unroll
    for (int kk = 0; kk < 2; ++kk) {
      bf16x8 af[2], bv[2];
#pragma unroll
      for (int m = 0; m < 2; ++m)
        af[m] = *(const bf16x8*)&As[(wr * 32 + m * 16 + lr) * 64 + kk * 32 + lk * 8];
#pragma unroll
      for (int n = 0; n < 2; ++n)
        bv[n] = *(const bf16x8*)&Bs[(wc * 32 + n * 16 + lr) * 64 + kk * 32 + lk * 8];
#pragma unroll
      for (int m = 0; m < 2; ++m)
#pragma unroll
        for (int n = 0; n < 2; ++n)
          acc[m][n] = __builtin_amdgcn_mfma_f32_16x16x32_bf16(af[m], bv[n], acc[m][n], 0, 0, 0);
    }
    __syncthreads();
  }
  const int row0 = bm * 64 + wr * 32 + lk * 4;
  const int col0 = bn * 64 + wc * 32 + lr;
#pragma unroll
  for (int m = 0; m < 2; ++m) {
#pragma unroll
    for (int n = 0; n < 2; ++n) {
      int col = col0 + n * 16;
      int nn = col >> 10, s = col & 1023;
#pragma unroll
      for (int j = 0; j < 4; ++j) {
        int c = row0 + m * 16 + j;
        out[((nn << 9) + 256 + c) * 1024 + s] = acc[m][n][j] + attn_b[c];
      }
    }
  }
}

extern "C" void kernel_launch(void* const* d_in, const int* in_sizes, int n_in,
                              void* d_out, int out_size, void* d_ws, size_t ws_size,
                              hipStream_t stream) {
  const float* x      = (const float*)d_in[0];
  const float* conv_w = (const float*)d_in[1];
  const float* conv_b = (const float*)d_in[2];
  const float* q_w    = (const float*)d_in[3];
  const float* q_b    = (const float*)d_in[4];
  const float* k_w    = (const float*)d_in[5];
  const float* k_b    = (const float*)d_in[6];
  const float* v_w    = (const float*)d_in[7];
  const float* v_b    = (const float*)d_in[8];
  const float* attn_w = (const float*)d_in[9];
  const float* attn_b = (const float*)d_in[10];
  const float* wm     = (const float*)d_in[11];
  const float* hm     = (const float*)d_in[12];
  float* out = (float*)d_out;
  char* ws = (char*)d_ws;

  // workspace layout (bytes), total ~42.6 MB
  u16*   W9   = (u16*)(ws + 0);         // 1024*2304*2 = 4,718,592
  u16*   W1   = (u16*)(ws + 4718592);   //  256*256*2  =   131,072
  u16*   xT   = (u16*)(ws + 4849664);   // 8192*256*2  = 4,194,304
  u16*   zpg  = (u16*)(ws + 9043968);   // 512*2       =     1,024
  u16*   qbf  = (u16*)(ws + 9044992);   // 64*1024*32*2= 4,194,304
  u16*   kbf  = (u16*)(ws + 13239296);  //               4,194,304
  u16*   vbf  = (u16*)(ws + 17433600);  //               4,194,304
  float* Bw   = (float*)(ws + 21627904);// 2M*4 =        8,388,608
  float* Bh   = (float*)(ws + 30016512);//               8,388,608
  u16*   AMT  = (u16*)(ws + 38405120);  // 8192*256*2 =  4,194,304

  hipLaunchKernelGGL(k_cast_w, dim3(1024), dim3(256), 0, stream,
                     conv_w, q_w, k_w, v_w, attn_w, W9, W1);
  hipLaunchKernelGGL(k_xT, dim3(2048), dim3(256), 0, stream, x, xT, zpg);
  hipLaunchKernelGGL(k_gemm_conv, dim3(8, 64), dim3(512), 0, stream,
                     W9, xT, zpg, out, qbf, kbf, vbf, conv_b, q_b, k_b, v_b);
  hipLaunchKernelGGL(k_bias, dim3(256), dim3(256), 0, stream, qbf, wm, hm, Bw, Bh);
  hipLaunchKernelGGL(k_attn, dim3(1024), dim3(256), 0, stream, qbf, kbf, vbf, Bw, Bh, AMT);
  hipLaunchKernelGGL(k_gemm_out, dim3(4, 128), dim3(256), 0, stream, W1, AMT, out, attn_b);
}